// Round 1
// baseline (190.308 us; speedup 1.0000x reference)
//
#include <hip/hip_runtime.h>

typedef __attribute__((ext_vector_type(8))) short short8;
typedef __attribute__((ext_vector_type(4))) float f32x4;

constexpr int Bc = 2, Nc = 2048, Dc = 1024, Hc = 16;   // dims
constexpr int Kc = 1024;                               // GEMM K
// M = B*N = 4096 for all GEMMs, Ncols = 1024

__device__ inline unsigned short f2bf(float f) {
  unsigned u = __builtin_bit_cast(unsigned, f);
  u = u + 0x7FFFu + ((u >> 16) & 1u);
  return (unsigned short)(u >> 16);
}
__device__ inline float bf2f(unsigned short h) {
  unsigned u = ((unsigned)h) << 16;
  return __builtin_bit_cast(float, u);
}

// ---------------- fp32 -> bf16 convert (8 elems/thread) ----------------
__global__ __launch_bounds__(256) void cvt_bf16(const float* __restrict__ src,
                                                unsigned short* __restrict__ dst, int n8) {
  int i = blockIdx.x * 256 + threadIdx.x;
  if (i >= n8) return;
  const float4* s = reinterpret_cast<const float4*>(src) + 2 * (size_t)i;
  float4 a = s[0], b = s[1];
  short8 o;
  o[0] = (short)f2bf(a.x); o[1] = (short)f2bf(a.y); o[2] = (short)f2bf(a.z); o[3] = (short)f2bf(a.w);
  o[4] = (short)f2bf(b.x); o[5] = (short)f2bf(b.y); o[6] = (short)f2bf(b.z); o[7] = (short)f2bf(b.w);
  *reinterpret_cast<short8*>(dst + (size_t)i * 8) = o;
}

// ---------------- bf16 GEMM: C[m][e] = sum_k A[m][k] * W[e][k] ----------------
// M=4096, Ncols=1024, K=1024. 128x128 tile, BK=32, 4 waves (2x2), 16x16x32 MFMA.
// MODE 0: scatter bf16 into (B,H,N,d) head layout. MODE 1: fp32 row-major out.
template<int MODE>
__global__ __launch_bounds__(256) void gemm_bt(const unsigned short* __restrict__ A,
                                               const unsigned short* __restrict__ W,
                                               void* __restrict__ Cout) {
  __shared__ unsigned short As[128][40];
  __shared__ unsigned short Bs[128][40];
  const int tid = threadIdx.x;
  const int bm = blockIdx.x & 31;   // 32 row tiles
  const int bn = blockIdx.x >> 5;   // 8 col tiles
  const int lane = tid & 63, wid = tid >> 6;
  const int wr = wid >> 1, wc = wid & 1;
  const int lr = lane & 15, lg = lane >> 4;

  f32x4 acc[4][4] = {};

  const int rowA = tid >> 1, half = tid & 1;
  const unsigned short* Ap = A + (size_t)(bm * 128 + rowA) * Kc + half * 16;
  const unsigned short* Wp = W + (size_t)(bn * 128 + rowA) * Kc + half * 16;

  for (int kt = 0; kt < Kc / 32; ++kt) {
    short8 a0 = *reinterpret_cast<const short8*>(Ap);
    short8 a1 = *reinterpret_cast<const short8*>(Ap + 8);
    short8 b0 = *reinterpret_cast<const short8*>(Wp);
    short8 b1 = *reinterpret_cast<const short8*>(Wp + 8);
    Ap += 32; Wp += 32;
    __syncthreads();
    *reinterpret_cast<short8*>(&As[rowA][half * 16])     = a0;
    *reinterpret_cast<short8*>(&As[rowA][half * 16 + 8]) = a1;
    *reinterpret_cast<short8*>(&Bs[rowA][half * 16])     = b0;
    *reinterpret_cast<short8*>(&Bs[rowA][half * 16 + 8]) = b1;
    __syncthreads();
    short8 af[4], bfv[4];
#pragma unroll
    for (int m = 0; m < 4; ++m)
      af[m] = *reinterpret_cast<const short8*>(&As[wr * 64 + m * 16 + lr][lg * 8]);
#pragma unroll
    for (int n = 0; n < 4; ++n)
      bfv[n] = *reinterpret_cast<const short8*>(&Bs[wc * 64 + n * 16 + lr][lg * 8]);
#pragma unroll
    for (int m = 0; m < 4; ++m)
#pragma unroll
      for (int n = 0; n < 4; ++n)
        acc[m][n] = __builtin_amdgcn_mfma_f32_16x16x32_bf16(af[m], bfv[n], acc[m][n], 0, 0, 0);
  }

#pragma unroll
  for (int m = 0; m < 4; ++m) {
#pragma unroll
    for (int n = 0; n < 4; ++n) {
#pragma unroll
      for (int r = 0; r < 4; ++r) {
        int grow = bm * 128 + wr * 64 + m * 16 + lg * 4 + r;
        int gcol = bn * 128 + wc * 64 + n * 16 + lr;
        float val = acc[m][n][r];
        if constexpr (MODE == 0) {
          unsigned short* Dst = (unsigned short*)Cout;
          int b = grow >> 11, nn = grow & 2047;
          int h = gcol >> 6, dd = gcol & 63;
          Dst[(((size_t)(b * 16 + h)) * 2048 + nn) * 64 + dd] = f2bf(val);
        } else {
          float* Dst = (float*)Cout;
          Dst[(size_t)grow * 1024 + gcol] = val;
        }
      }
    }
  }
}

// ---------------- q2[row] = sum_d qk[row][d]^2  (rows = B*H*N = 65536) ----------------
__global__ __launch_bounds__(256) void q2_kernel(const unsigned short* __restrict__ qk,
                                                 float* __restrict__ q2) {
  int t = blockIdx.x * 256 + threadIdx.x;
  int row = t >> 2, q = t & 3;
  const short8* p = reinterpret_cast<const short8*>(qk + (size_t)row * 64 + q * 16);
  short8 v0 = p[0], v1 = p[1];
  float s = 0.f;
#pragma unroll
  for (int i = 0; i < 8; ++i) {
    float f0 = bf2f((unsigned short)v0[i]);
    float f1 = bf2f((unsigned short)v1[i]);
    s += f0 * f0 + f1 * f1;
  }
  s += __shfl_xor(s, 1);
  s += __shfl_xor(s, 2);
  if (q == 0) q2[row] = s;
}

// ---------------- fused distance-attention ----------------
// grid: B*H * (N/128). block 256 (4 waves). Each wave: 32 q-rows x full d=64.
// K-tiles of 64 keys. p = exp(2*dot - q2_i - q2_j) <= ~1 (max logit is 0 on diagonal)
// -> no online rescale needed. num via MFMA, den per-lane + shuffle reduce.
__global__ __launch_bounds__(256) void attn_kernel(const unsigned short* __restrict__ qk,
                                                   const unsigned short* __restrict__ vin,
                                                   const float* __restrict__ q2,
                                                   unsigned short* __restrict__ wout) {
  __shared__ unsigned short Ks[64][72];
  __shared__ unsigned short Vt[64][72];   // Vt[dd][j] = V[j][dd]
  __shared__ unsigned short Ps[128][72];
  const int tid = threadIdx.x;
  const int bh = blockIdx.x >> 4;   // 0..31
  const int qt = blockIdx.x & 15;
  const int b = bh >> 4, h = bh & 15;
  const unsigned short* Qg = qk + (size_t)bh * Nc * 64;
  const unsigned short* Vg = vin + (size_t)bh * Nc * 64;
  const float* q2g = q2 + (size_t)bh * Nc;
  const int lane = tid & 63, wid = tid >> 6;
  const int lr = lane & 15, lg = lane >> 4;

  const int qbase = qt * 128 + wid * 32;

  // Q fragments in registers (A-operand: row=lr, k = kh*32 + lg*8 + t)
  short8 qf[2][2];
#pragma unroll
  for (int qb = 0; qb < 2; ++qb)
#pragma unroll
    for (int kh = 0; kh < 2; ++kh)
      qf[qb][kh] = *reinterpret_cast<const short8*>(
          Qg + (size_t)(qbase + qb * 16 + lr) * 64 + kh * 32 + lg * 8);

  float q2r[2][4];
#pragma unroll
  for (int qb = 0; qb < 2; ++qb)
#pragma unroll
    for (int r = 0; r < 4; ++r)
      q2r[qb][r] = q2g[qbase + qb * 16 + lg * 4 + r];

  f32x4 wacc[2][4] = {};
  float denp[2][4] = {};

  for (int kt = 0; kt < Nc / 64; ++kt) {
    __syncthreads();
    {  // stage K tile (64x64)
      int row = tid >> 2, quad = tid & 3;
      const short8* g = reinterpret_cast<const short8*>(
          Qg + (size_t)(kt * 64 + row) * 64 + quad * 16);
      short8 k0 = g[0], k1 = g[1];
      *reinterpret_cast<short8*>(&Ks[row][quad * 16])     = k0;
      *reinterpret_cast<short8*>(&Ks[row][quad * 16 + 8]) = k1;
    }
    {  // stage V transposed
#pragma unroll
      for (int uu = 0; uu < 2; ++uu) {
        int u = tid + uu * 256;
        int j = u >> 3, dg = u & 7;
        short8 vv = *reinterpret_cast<const short8*>(
            Vg + (size_t)(kt * 64 + j) * 64 + dg * 8);
#pragma unroll
        for (int i = 0; i < 8; ++i) Vt[dg * 8 + i][j] = (unsigned short)vv[i];
      }
    }
    __syncthreads();

    // K fragments (B-operand: col=lr -> key, k = kh*32 + lg*8 + t)
    short8 kf[4][2];
#pragma unroll
    for (int jb = 0; jb < 4; ++jb)
#pragma unroll
      for (int kh = 0; kh < 2; ++kh)
        kf[jb][kh] = *reinterpret_cast<const short8*>(&Ks[jb * 16 + lr][kh * 32 + lg * 8]);

    float k2v[4];
#pragma unroll
    for (int jb = 0; jb < 4; ++jb) k2v[jb] = q2g[kt * 64 + jb * 16 + lr];

    // S = Q.K^T ; P = exp(2S - q2i - q2j) -> Ps (bf16), den partial
#pragma unroll
    for (int qb = 0; qb < 2; ++qb) {
#pragma unroll
      for (int jb = 0; jb < 4; ++jb) {
        f32x4 s = {};
        s = __builtin_amdgcn_mfma_f32_16x16x32_bf16(qf[qb][0], kf[jb][0], s, 0, 0, 0);
        s = __builtin_amdgcn_mfma_f32_16x16x32_bf16(qf[qb][1], kf[jb][1], s, 0, 0, 0);
#pragma unroll
        for (int r = 0; r < 4; ++r) {
          float l = 2.f * s[r] - q2r[qb][r] - k2v[jb];
          float p = __expf(l);
          unsigned short pb = f2bf(p);
          denp[qb][r] += bf2f(pb);
          Ps[wid * 32 + qb * 16 + lg * 4 + r][jb * 16 + lr] = pb;
        }
      }
    }

    // PV: wacc[qb][db] += P(32x64) @ V(64x64). Ps rows are wave-private (no barrier).
    short8 vf[4][2];
#pragma unroll
    for (int db = 0; db < 4; ++db)
#pragma unroll
      for (int jh = 0; jh < 2; ++jh)
        vf[db][jh] = *reinterpret_cast<const short8*>(&Vt[db * 16 + lr][jh * 32 + lg * 8]);
    short8 pf[2][2];
#pragma unroll
    for (int qb = 0; qb < 2; ++qb)
#pragma unroll
      for (int jh = 0; jh < 2; ++jh)
        pf[qb][jh] = *reinterpret_cast<const short8*>(&Ps[wid * 32 + qb * 16 + lr][jh * 32 + lg * 8]);
#pragma unroll
    for (int qb = 0; qb < 2; ++qb)
#pragma unroll
      for (int db = 0; db < 4; ++db) {
        wacc[qb][db] = __builtin_amdgcn_mfma_f32_16x16x32_bf16(pf[qb][0], vf[db][0], wacc[qb][db], 0, 0, 0);
        wacc[qb][db] = __builtin_amdgcn_mfma_f32_16x16x32_bf16(pf[qb][1], vf[db][1], wacc[qb][db], 0, 0, 0);
      }
  }

  // reduce den across the 16 lanes of each row group, then write w = num/den
  float inv[2][4];
#pragma unroll
  for (int qb = 0; qb < 2; ++qb)
#pragma unroll
    for (int r = 0; r < 4; ++r) {
      float s = denp[qb][r];
      s += __shfl_xor(s, 1);
      s += __shfl_xor(s, 2);
      s += __shfl_xor(s, 4);
      s += __shfl_xor(s, 8);
      inv[qb][r] = 1.f / s;
    }
#pragma unroll
  for (int qb = 0; qb < 2; ++qb)
#pragma unroll
    for (int db = 0; db < 4; ++db)
#pragma unroll
      for (int r = 0; r < 4; ++r) {
        int nn = qt * 128 + wid * 32 + qb * 16 + lg * 4 + r;
        wout[((size_t)b * Nc + nn) * 1024 + h * 64 + db * 16 + lr] =
            f2bf(wacc[qb][db][r] * inv[qb][r]);
      }
}

extern "C" void kernel_launch(void* const* d_in, const int* in_sizes, int n_in,
                              void* d_out, int out_size, void* d_ws, size_t ws_size,
                              hipStream_t stream) {
  const float* x    = (const float*)d_in[0];
  const float* Wqk  = (const float*)d_in[1];
  const float* Wv   = (const float*)d_in[2];
  const float* Wout = (const float*)d_in[3];
  float* out = (float*)d_out;
  char* ws = (char*)d_ws;

  // workspace layout (bytes)
  unsigned short* x_bf    = (unsigned short*)(ws + 0);          //  8 MB  (4096x1024)
  unsigned short* wqk_bf  = (unsigned short*)(ws + 8388608);    //  2 MB
  unsigned short* wv_bf   = (unsigned short*)(ws + 10485760);   //  2 MB
  unsigned short* wout_bf = (unsigned short*)(ws + 12582912);   //  2 MB
  unsigned short* qk_buf  = (unsigned short*)(ws + 14680064);   //  8 MB (B,H,N,d)
  unsigned short* v_buf   = (unsigned short*)(ws + 23068672);   //  8 MB (B,H,N,d)
  float*          q2_buf  = (float*)        (ws + 31457280);    // 256 KB (B,H,N)
  unsigned short* w_buf   = (unsigned short*)(ws + 31719424);   //  8 MB (B,N,D)

  cvt_bf16<<<2048, 256, 0, stream>>>(x, x_bf, 524288);
  cvt_bf16<<<512, 256, 0, stream>>>(Wqk, wqk_bf, 131072);
  cvt_bf16<<<512, 256, 0, stream>>>(Wv, wv_bf, 131072);
  cvt_bf16<<<512, 256, 0, stream>>>(Wout, wout_bf, 131072);

  gemm_bt<0><<<256, 256, 0, stream>>>(x_bf, wqk_bf, (void*)qk_buf);
  gemm_bt<0><<<256, 256, 0, stream>>>(x_bf, wv_bf, (void*)v_buf);

  q2_kernel<<<1024, 256, 0, stream>>>(qk_buf, q2_buf);

  attn_kernel<<<512, 256, 0, stream>>>(qk_buf, v_buf, q2_buf, w_buf);

  gemm_bt<1><<<256, 256, 0, stream>>>(w_buf, wout_bf, (void*)out);
}

// Round 2
// 158.360 us; speedup vs baseline: 1.2017x; 1.2017x over previous
//
#include <hip/hip_runtime.h>

typedef __attribute__((ext_vector_type(8))) short short8;
typedef __attribute__((ext_vector_type(4))) float f32x4;
typedef __attribute__((ext_vector_type(4))) unsigned short ushort4v;

constexpr int Nc = 2048, Kc = 1024;

__device__ inline unsigned short f2bf(float f) {
  unsigned u = __builtin_bit_cast(unsigned, f);
  u = u + 0x7FFFu + ((u >> 16) & 1u);
  return (unsigned short)(u >> 16);
}
__device__ inline float bf2f(unsigned short h) {
  unsigned u = ((unsigned)h) << 16;
  return __builtin_bit_cast(float, u);
}

__device__ inline void gload_lds16(const void* g, void* l) {
  __builtin_amdgcn_global_load_lds(
      (const __attribute__((address_space(1))) unsigned int*)g,
      (__attribute__((address_space(3))) unsigned int*)l, 16, 0, 0);
}

// ---------------- fp32 -> bf16 convert (8 elems/thread) ----------------
__global__ __launch_bounds__(256) void cvt_bf16(const float* __restrict__ src,
                                                unsigned short* __restrict__ dst, int n8) {
  int i = blockIdx.x * 256 + threadIdx.x;
  if (i >= n8) return;
  const float4* s = reinterpret_cast<const float4*>(src) + 2 * (size_t)i;
  float4 a = s[0], b = s[1];
  short8 o;
  o[0] = (short)f2bf(a.x); o[1] = (short)f2bf(a.y); o[2] = (short)f2bf(a.z); o[3] = (short)f2bf(a.w);
  o[4] = (short)f2bf(b.x); o[5] = (short)f2bf(b.y); o[6] = (short)f2bf(b.z); o[7] = (short)f2bf(b.w);
  *reinterpret_cast<short8*>(dst + (size_t)i * 8) = o;
}

// ---------------- bf16 GEMM: C[m][e] = sum_k A[m][k] * W[e][k] ----------------
// m97 structure: 128x128 tile, BK=64, global_load_lds w16, XOR-swizzled LDS.
// MODE 0: bf16 scatter to (B,H,N,d). MODE 1: fp32 row-major. MODE 2: bf16 scatter to (B,H,d,N).
template<int MODE>
__global__ __launch_bounds__(256) void gemm_bt(const unsigned short* __restrict__ A,
                                               const unsigned short* __restrict__ W,
                                               void* __restrict__ Cout) {
  __shared__ unsigned short As[128 * 64];
  __shared__ unsigned short Bs[128 * 64];
  const int tid = threadIdx.x;
  const int bm = blockIdx.x & 31;   // 32 row tiles
  const int bn = blockIdx.x >> 5;   // 8 col tiles
  const int lane = tid & 63, wid = tid >> 6;
  const int wr = wid >> 1, wc = wid & 1;
  const int lr = lane & 15, lg = lane >> 4;

  f32x4 acc[4][4] = {};

  const unsigned short* Abase = A + (size_t)bm * 128 * Kc;
  const unsigned short* Wbase = W + (size_t)bn * 128 * Kc;

  for (int kt = 0; kt < Kc / 64; ++kt) {
    __syncthreads();   // all reads of LDS from prev iter done
#pragma unroll
    for (int r = 0; r < 4; ++r) {
      int idx = r * 256 + tid;
      int row = idx >> 3, cc = idx & 7;
      int cs = cc ^ (row & 7);
      unsigned short* dstA = &As[(r * 256 + wid * 64) * 8];
      unsigned short* dstB = &Bs[(r * 256 + wid * 64) * 8];
      gload_lds16(Abase + (size_t)row * Kc + kt * 64 + cs * 8, dstA);
      gload_lds16(Wbase + (size_t)row * Kc + kt * 64 + cs * 8, dstB);
    }
    __syncthreads();   // drains vmcnt -> LDS tiles ready

    short8 af[4][2], bfv[4][2];
#pragma unroll
    for (int m = 0; m < 4; ++m) {
      int row = wr * 64 + m * 16 + lr;
#pragma unroll
      for (int kh = 0; kh < 2; ++kh) {
        int cs = (kh * 4 + lg) ^ (row & 7);
        af[m][kh] = *reinterpret_cast<const short8*>(&As[row * 64 + cs * 8]);
      }
    }
#pragma unroll
    for (int n = 0; n < 4; ++n) {
      int row = wc * 64 + n * 16 + lr;
#pragma unroll
      for (int kh = 0; kh < 2; ++kh) {
        int cs = (kh * 4 + lg) ^ (row & 7);
        bfv[n][kh] = *reinterpret_cast<const short8*>(&Bs[row * 64 + cs * 8]);
      }
    }
#pragma unroll
    for (int kh = 0; kh < 2; ++kh)
#pragma unroll
      for (int m = 0; m < 4; ++m)
#pragma unroll
        for (int n = 0; n < 4; ++n)
          acc[m][n] = __builtin_amdgcn_mfma_f32_16x16x32_bf16(af[m][kh], bfv[n][kh], acc[m][n], 0, 0, 0);
  }

#pragma unroll
  for (int m = 0; m < 4; ++m) {
#pragma unroll
    for (int n = 0; n < 4; ++n) {
      int grow0 = bm * 128 + wr * 64 + m * 16 + lg * 4;
      int gcol = bn * 128 + wc * 64 + n * 16 + lr;
      if constexpr (MODE == 2) {
        // V transposed head layout: Dst[((b*16+h)*64+dd)*2048 + nn]
        int b = grow0 >> 11, nn0 = grow0 & 2047;
        int h = gcol >> 6, dd = gcol & 63;
        ushort4v pk;
#pragma unroll
        for (int r = 0; r < 4; ++r) pk[r] = f2bf(acc[m][n][r]);
        unsigned short* Dst = (unsigned short*)Cout;
        *reinterpret_cast<ushort4v*>(&Dst[(((size_t)(b * 16 + h)) * 64 + dd) * 2048 + nn0]) = pk;
      } else {
#pragma unroll
        for (int r = 0; r < 4; ++r) {
          int grow = grow0 + r;
          float val = acc[m][n][r];
          if constexpr (MODE == 0) {
            unsigned short* Dst = (unsigned short*)Cout;
            int b = grow >> 11, nn = grow & 2047;
            int h = gcol >> 6, dd = gcol & 63;
            Dst[(((size_t)(b * 16 + h)) * 2048 + nn) * 64 + dd] = f2bf(val);
          } else {
            float* Dst = (float*)Cout;
            Dst[(size_t)grow * 1024 + gcol] = val;
          }
        }
      }
    }
  }
}

// ---------------- q2[row] = sum_d qk[row][d]^2  (rows = B*H*N = 65536) ----------------
__global__ __launch_bounds__(256) void q2_kernel(const unsigned short* __restrict__ qk,
                                                 float* __restrict__ q2) {
  int t = blockIdx.x * 256 + threadIdx.x;
  int row = t >> 2, q = t & 3;
  const short8* p = reinterpret_cast<const short8*>(qk + (size_t)row * 64 + q * 16);
  short8 v0 = p[0], v1 = p[1];
  float s = 0.f;
#pragma unroll
  for (int i = 0; i < 8; ++i) {
    float f0 = bf2f((unsigned short)v0[i]);
    float f1 = bf2f((unsigned short)v1[i]);
    s += f0 * f0 + f1 * f1;
  }
  s += __shfl_xor(s, 1);
  s += __shfl_xor(s, 2);
  if (q == 0) q2[row] = s;
}

// ---------------- fused distance-attention ----------------
// grid: 32 bh * 16 qtiles. 4 waves; wave = 32 q-rows. K-tiles of 64 keys,
// double-buffered via global_load_lds (XOR-swizzled source, swizzled reads).
// p = exp(2*dot - q2i - q2j) <= 1 (max logit 0 on diagonal) -> no online rescale.
__global__ __launch_bounds__(256) void attn_kernel(const unsigned short* __restrict__ qk,
                                                   const unsigned short* __restrict__ vt,
                                                   const float* __restrict__ q2,
                                                   unsigned short* __restrict__ wout) {
  __shared__ unsigned short Ks[2][64 * 64];
  __shared__ unsigned short Vs[2][64 * 64];
  __shared__ unsigned short Ps[128][72];
  const int tid = threadIdx.x;
  const int bh = blockIdx.x >> 4;
  const int qt = blockIdx.x & 15;
  const int b = bh >> 4, h = bh & 15;
  const unsigned short* Qg = qk + (size_t)bh * Nc * 64;
  const unsigned short* Vg = vt + (size_t)bh * 64 * Nc;   // (d, N) layout
  const float* q2g = q2 + (size_t)bh * Nc;
  const int lane = tid & 63, wid = tid >> 6;
  const int lr = lane & 15, lg = lane >> 4;

  const int qbase = qt * 128 + wid * 32;

  // Q fragments in registers (A-operand: row=lr, k = kh*32 + lg*8 + t)
  short8 qf[2][2];
#pragma unroll
  for (int qb = 0; qb < 2; ++qb)
#pragma unroll
    for (int kh = 0; kh < 2; ++kh)
      qf[qb][kh] = *reinterpret_cast<const short8*>(
          Qg + (size_t)(qbase + qb * 16 + lr) * 64 + kh * 32 + lg * 8);

  float q2r[2][4];
#pragma unroll
  for (int qb = 0; qb < 2; ++qb)
#pragma unroll
    for (int r = 0; r < 4; ++r)
      q2r[qb][r] = q2g[qbase + qb * 16 + lg * 4 + r];

  f32x4 wacc[2][4] = {};
  float denp[2][4] = {};

  auto stage = [&](int kt, int s) {
#pragma unroll
    for (int r = 0; r < 2; ++r) {
      int idx = r * 256 + tid;
      int row = idx >> 3, cc = idx & 7;
      int cs = cc ^ (row & 7);
      gload_lds16(Qg + (size_t)(kt * 64 + row) * 64 + cs * 8, &Ks[s][(r * 256 + wid * 64) * 8]);
      gload_lds16(Vg + (size_t)row * Nc + kt * 64 + cs * 8, &Vs[s][(r * 256 + wid * 64) * 8]);
    }
  };

  stage(0, 0);
  __syncthreads();

  for (int kt = 0; kt < Nc / 64; ++kt) {
    const int cur = kt & 1;
    if (kt + 1 < Nc / 64) stage(kt + 1, cur ^ 1);   // overlap with compute

    // K fragments (B-operand: col=lr -> key, k = kh*32 + lg*8 + t)
    short8 kf[4][2];
#pragma unroll
    for (int jb = 0; jb < 4; ++jb) {
      int row = jb * 16 + lr;
#pragma unroll
      for (int kh = 0; kh < 2; ++kh) {
        int cs = (kh * 4 + lg) ^ (row & 7);
        kf[jb][kh] = *reinterpret_cast<const short8*>(&Ks[cur][row * 64 + cs * 8]);
      }
    }
    float k2v[4];
#pragma unroll
    for (int jb = 0; jb < 4; ++jb) k2v[jb] = q2g[kt * 64 + jb * 16 + lr];

    // S = Q.K^T ; P = exp(2S - q2i - q2j) -> Ps (bf16), den partial (f32)
#pragma unroll
    for (int qb = 0; qb < 2; ++qb) {
#pragma unroll
      for (int jb = 0; jb < 4; ++jb) {
        f32x4 s = {};
        s = __builtin_amdgcn_mfma_f32_16x16x32_bf16(qf[qb][0], kf[jb][0], s, 0, 0, 0);
        s = __builtin_amdgcn_mfma_f32_16x16x32_bf16(qf[qb][1], kf[jb][1], s, 0, 0, 0);
#pragma unroll
        for (int r = 0; r < 4; ++r) {
          float l = 2.f * s[r] - q2r[qb][r] - k2v[jb];
          float p = __expf(l);
          denp[qb][r] += p;
          Ps[wid * 32 + qb * 16 + lg * 4 + r][jb * 16 + lr] = f2bf(p);
        }
      }
    }

    // PV: wacc += P(32x64) @ V(64x64); V already transposed in LDS (row = dd).
    short8 vf[4][2];
#pragma unroll
    for (int db = 0; db < 4; ++db) {
      int row = db * 16 + lr;
#pragma unroll
      for (int jh = 0; jh < 2; ++jh) {
        int cs = (jh * 4 + lg) ^ (row & 7);
        vf[db][jh] = *reinterpret_cast<const short8*>(&Vs[cur][row * 64 + cs * 8]);
      }
    }
    short8 pf[2][2];
#pragma unroll
    for (int qb = 0; qb < 2; ++qb)
#pragma unroll
      for (int jh = 0; jh < 2; ++jh)
        pf[qb][jh] = *reinterpret_cast<const short8*>(&Ps[wid * 32 + qb * 16 + lr][jh * 32 + lg * 8]);
#pragma unroll
    for (int qb = 0; qb < 2; ++qb)
#pragma unroll
      for (int db = 0; db < 4; ++db) {
        wacc[qb][db] = __builtin_amdgcn_mfma_f32_16x16x32_bf16(pf[qb][0], vf[db][0], wacc[qb][db], 0, 0, 0);
        wacc[qb][db] = __builtin_amdgcn_mfma_f32_16x16x32_bf16(pf[qb][1], vf[db][1], wacc[qb][db], 0, 0, 0);
      }
    __syncthreads();   // reads of buf[cur] done everywhere; staged buf[cur^1] drained
  }

  // reduce den across 16 lanes of each row group; write w = num/den
  float inv[2][4];
#pragma unroll
  for (int qb = 0; qb < 2; ++qb)
#pragma unroll
    for (int r = 0; r < 4; ++r) {
      float s = denp[qb][r];
      s += __shfl_xor(s, 1);
      s += __shfl_xor(s, 2);
      s += __shfl_xor(s, 4);
      s += __shfl_xor(s, 8);
      inv[qb][r] = 1.f / s;
    }
#pragma unroll
  for (int qb = 0; qb < 2; ++qb)
#pragma unroll
    for (int db = 0; db < 4; ++db)
#pragma unroll
      for (int r = 0; r < 4; ++r) {
        int nn = qt * 128 + wid * 32 + qb * 16 + lg * 4 + r;
        wout[((size_t)b * Nc + nn) * 1024 + h * 64 + db * 16 + lr] =
            f2bf(wacc[qb][db][r] * inv[qb][r]);
      }
}

extern "C" void kernel_launch(void* const* d_in, const int* in_sizes, int n_in,
                              void* d_out, int out_size, void* d_ws, size_t ws_size,
                              hipStream_t stream) {
  const float* x    = (const float*)d_in[0];
  const float* Wqk  = (const float*)d_in[1];
  const float* Wv   = (const float*)d_in[2];
  const float* Wout = (const float*)d_in[3];
  float* out = (float*)d_out;
  char* ws = (char*)d_ws;

  unsigned short* x_bf    = (unsigned short*)(ws + 0);          //  8 MB
  unsigned short* wqk_bf  = (unsigned short*)(ws + 8388608);    //  2 MB
  unsigned short* wv_bf   = (unsigned short*)(ws + 10485760);   //  2 MB
  unsigned short* wout_bf = (unsigned short*)(ws + 12582912);   //  2 MB
  unsigned short* qk_buf  = (unsigned short*)(ws + 14680064);   //  8 MB (B,H,N,d)
  unsigned short* vt_buf  = (unsigned short*)(ws + 23068672);   //  8 MB (B,H,d,N)
  float*          q2_buf  = (float*)        (ws + 31457280);    // 256 KB
  unsigned short* w_buf   = (unsigned short*)(ws + 31719424);   //  8 MB (B,N,D)

  cvt_bf16<<<2048, 256, 0, stream>>>(x, x_bf, 524288);
  cvt_bf16<<<512, 256, 0, stream>>>(Wqk, wqk_bf, 131072);
  cvt_bf16<<<512, 256, 0, stream>>>(Wv, wv_bf, 131072);
  cvt_bf16<<<512, 256, 0, stream>>>(Wout, wout_bf, 131072);

  gemm_bt<0><<<256, 256, 0, stream>>>(x_bf, wqk_bf, (void*)qk_buf);
  gemm_bt<2><<<256, 256, 0, stream>>>(x_bf, wv_bf, (void*)vt_buf);

  q2_kernel<<<1024, 256, 0, stream>>>(qk_buf, q2_buf);

  attn_kernel<<<512, 256, 0, stream>>>(qk_buf, vt_buf, q2_buf, w_buf);

  gemm_bt<1><<<256, 256, 0, stream>>>(w_buf, wout_bf, (void*)out);
}

// Round 4
// 141.862 us; speedup vs baseline: 1.3415x; 1.1163x over previous
//
#include <hip/hip_runtime.h>

typedef __attribute__((ext_vector_type(8))) short short8;
typedef __attribute__((ext_vector_type(4))) float f32x4;
typedef __attribute__((ext_vector_type(16))) float f32x16;
typedef __attribute__((ext_vector_type(4))) unsigned short ushort4v;
typedef __attribute__((ext_vector_type(4))) unsigned int uint4v;
typedef __attribute__((ext_vector_type(2))) unsigned int uint2v;

constexpr int Nc = 2048, Kc = 1024;
constexpr float LOG2E = 1.4426950408889634f;

__device__ inline unsigned short f2bf(float f) {
  unsigned u = __builtin_bit_cast(unsigned, f);
  u = u + 0x7FFFu + ((u >> 16) & 1u);
  return (unsigned short)(u >> 16);
}
__device__ inline float bf2f(unsigned short h) {
  unsigned u = ((unsigned)h) << 16;
  return __builtin_bit_cast(float, u);
}
__device__ inline float fexp2(float x) {
  float r;
  asm("v_exp_f32 %0, %1" : "=v"(r) : "v"(x));
  return r;
}
__device__ inline unsigned cvt_pk_bf16(float lo, float hi) {
  unsigned r;
  asm("v_cvt_pk_bf16_f32 %0, %1, %2" : "=v"(r) : "v"(lo), "v"(hi));
  return r;
}

__device__ inline void gload_lds16(const void* g, void* l) {
  __builtin_amdgcn_global_load_lds(
      (const __attribute__((address_space(1))) unsigned int*)g,
      (__attribute__((address_space(3))) unsigned int*)l, 16, 0, 0);
}
__device__ inline void gload_lds4(const void* g, void* l) {
  __builtin_amdgcn_global_load_lds(
      (const __attribute__((address_space(1))) unsigned int*)g,
      (__attribute__((address_space(3))) unsigned int*)l, 4, 0, 0);
}

// ---------------- fp32 -> bf16 convert (8 elems/thread) ----------------
__global__ __launch_bounds__(256) void cvt_bf16(const float* __restrict__ src,
                                                unsigned short* __restrict__ dst, int n8) {
  int i = blockIdx.x * 256 + threadIdx.x;
  if (i >= n8) return;
  const float4* s = reinterpret_cast<const float4*>(src) + 2 * (size_t)i;
  float4 a = s[0], b = s[1];
  short8 o;
  o[0] = (short)f2bf(a.x); o[1] = (short)f2bf(a.y); o[2] = (short)f2bf(a.z); o[3] = (short)f2bf(a.w);
  o[4] = (short)f2bf(b.x); o[5] = (short)f2bf(b.y); o[6] = (short)f2bf(b.z); o[7] = (short)f2bf(b.w);
  *reinterpret_cast<short8*>(dst + (size_t)i * 8) = o;
}

// ---------------- bf16 GEMM: C[m][e] = sum_k A[m][k] * W[e][k] ----------------
// MODE 0: bf16 scatter to (B,H,N,d). MODE 1: fp32 row-major.
// MODE 2: bf16 scatter to (B,H,d,N), scaled by ek[b,h,n] (V' = ek * V).
template<int MODE>
__global__ __launch_bounds__(256) void gemm_bt(const unsigned short* __restrict__ A,
                                               const unsigned short* __restrict__ W,
                                               void* __restrict__ Cout,
                                               const float* __restrict__ ekg) {
  __shared__ unsigned short As[128 * 64];
  __shared__ unsigned short Bs[128 * 64];
  const int tid = threadIdx.x;
  const int bm = blockIdx.x & 31;
  const int bn = blockIdx.x >> 5;
  const int lane = tid & 63, wid = tid >> 6;
  const int wr = wid >> 1, wc = wid & 1;
  const int lr = lane & 15, lg = lane >> 4;

  f32x4 acc[4][4] = {};

  const unsigned short* Abase = A + (size_t)bm * 128 * Kc;
  const unsigned short* Wbase = W + (size_t)bn * 128 * Kc;

  for (int kt = 0; kt < Kc / 64; ++kt) {
    __syncthreads();
#pragma unroll
    for (int r = 0; r < 4; ++r) {
      int idx = r * 256 + tid;
      int row = idx >> 3, cc = idx & 7;
      int cs = cc ^ (row & 7);
      unsigned short* dstA = &As[(r * 256 + wid * 64) * 8];
      unsigned short* dstB = &Bs[(r * 256 + wid * 64) * 8];
      gload_lds16(Abase + (size_t)row * Kc + kt * 64 + cs * 8, dstA);
      gload_lds16(Wbase + (size_t)row * Kc + kt * 64 + cs * 8, dstB);
    }
    __syncthreads();

    short8 af[4][2], bfv[4][2];
#pragma unroll
    for (int m = 0; m < 4; ++m) {
      int row = wr * 64 + m * 16 + lr;
#pragma unroll
      for (int kh = 0; kh < 2; ++kh) {
        int cs = (kh * 4 + lg) ^ (row & 7);
        af[m][kh] = *reinterpret_cast<const short8*>(&As[row * 64 + cs * 8]);
      }
    }
#pragma unroll
    for (int n = 0; n < 4; ++n) {
      int row = wc * 64 + n * 16 + lr;
#pragma unroll
      for (int kh = 0; kh < 2; ++kh) {
        int cs = (kh * 4 + lg) ^ (row & 7);
        bfv[n][kh] = *reinterpret_cast<const short8*>(&Bs[row * 64 + cs * 8]);
      }
    }
#pragma unroll
    for (int kh = 0; kh < 2; ++kh)
#pragma unroll
      for (int m = 0; m < 4; ++m)
#pragma unroll
        for (int n = 0; n < 4; ++n)
          acc[m][n] = __builtin_amdgcn_mfma_f32_16x16x32_bf16(af[m][kh], bfv[n][kh], acc[m][n], 0, 0, 0);
  }

#pragma unroll
  for (int m = 0; m < 4; ++m) {
#pragma unroll
    for (int n = 0; n < 4; ++n) {
      int grow0 = bm * 128 + wr * 64 + m * 16 + lg * 4;
      int gcol = bn * 128 + wc * 64 + n * 16 + lr;
      if constexpr (MODE == 2) {
        int b = grow0 >> 11, nn0 = grow0 & 2047;
        int h = gcol >> 6, dd = gcol & 63;
        float4 ekq = *reinterpret_cast<const float4*>(&ekg[((size_t)(b * 16 + h)) * 2048 + nn0]);
        ushort4v pk;
        pk[0] = f2bf(acc[m][n][0] * ekq.x);
        pk[1] = f2bf(acc[m][n][1] * ekq.y);
        pk[2] = f2bf(acc[m][n][2] * ekq.z);
        pk[3] = f2bf(acc[m][n][3] * ekq.w);
        unsigned short* Dst = (unsigned short*)Cout;
        *reinterpret_cast<ushort4v*>(&Dst[(((size_t)(b * 16 + h)) * 64 + dd) * 2048 + nn0]) = pk;
      } else {
#pragma unroll
        for (int r = 0; r < 4; ++r) {
          int grow = grow0 + r;
          float val = acc[m][n][r];
          if constexpr (MODE == 0) {
            unsigned short* Dst = (unsigned short*)Cout;
            int b = grow >> 11, nn = grow & 2047;
            int h = gcol >> 6, dd = gcol & 63;
            Dst[(((size_t)(b * 16 + h)) * 2048 + nn) * 64 + dd] = f2bf(val);
          } else {
            float* Dst = (float*)Cout;
            Dst[(size_t)grow * 1024 + gcol] = val;
          }
        }
      }
    }
  }
}

// -------- q2l[row] = log2e * ||qk_row||^2 ; ek[row] = exp(-||qk_row||^2) --------
__global__ __launch_bounds__(256) void q2ek_kernel(const unsigned short* __restrict__ qk,
                                                   float* __restrict__ q2l,
                                                   float* __restrict__ ek) {
  int t = blockIdx.x * 256 + threadIdx.x;
  int row = t >> 2, q = t & 3;
  const short8* p = reinterpret_cast<const short8*>(qk + (size_t)row * 64 + q * 16);
  short8 v0 = p[0], v1 = p[1];
  float s = 0.f;
#pragma unroll
  for (int i = 0; i < 8; ++i) {
    float f0 = bf2f((unsigned short)v0[i]);
    float f1 = bf2f((unsigned short)v1[i]);
    s += f0 * f0 + f1 * f1;
  }
  s += __shfl_xor(s, 1);
  s += __shfl_xor(s, 2);
  if (q == 0) {
    q2l[row] = s * LOG2E;
    ek[row] = __expf(-s);
  }
}

// ---------------- fused distance-attention (T12 structure) ----------------
// 1024 blocks x 128 threads (2 waves, 32 q-rows each). 64-key tiles, dbuf LDS.
// S^T = mfma_32x32x16(K, Q); g = exp2(2log2e*s - q2l) in-register;
// P-frags via cvt_pk + permlane32_swap; V pre-scaled by ek; den = sum g*ek.
__global__ __launch_bounds__(128) void attn_kernel(const unsigned short* __restrict__ qk,
                                                   const unsigned short* __restrict__ vt,
                                                   const float* __restrict__ q2lg_,
                                                   const float* __restrict__ ekg_,
                                                   unsigned short* __restrict__ wout) {
  __shared__ unsigned short Ks[2][64 * 64];
  __shared__ unsigned short Vs[2][64 * 64];
  __shared__ float ekLds[2][64];
  __shared__ float invLds[2][32];

  const int tid = threadIdx.x;
  // XCD-chunked swizzle: blocks sharing a bh land on one XCD's L2 (1024 % 8 == 0)
  const int orig = (blockIdx.x & 7) * 128 + (blockIdx.x >> 3);
  const int bh = orig >> 5;          // 0..31
  const int qt = orig & 31;          // 32 q-tiles of 64 rows
  const int b = bh >> 4, h = bh & 15;
  const unsigned short* Qg = qk + (size_t)bh * Nc * 64;
  const unsigned short* Vg = vt + (size_t)bh * 64 * Nc;
  const float* q2lg = q2lg_ + (size_t)bh * Nc;
  const float* ekg = ekg_ + (size_t)bh * Nc;
  const int lane = tid & 63, wid = tid >> 6;
  const int lo = lane & 31, hi = lane >> 5;

  const int qbase = qt * 64 + wid * 32;

  // Q fragments (B-operand of 32x32x16: col=qrow=lo, k = kk*16 + hi*8 + t)
  short8 qf[4];
#pragma unroll
  for (int kk = 0; kk < 4; ++kk)
    qf[kk] = *reinterpret_cast<const short8*>(
        Qg + (size_t)(qbase + lo) * 64 + kk * 16 + hi * 8);

  const float q2l_r = q2lg[qbase + lo];

  f32x16 wacc0 = {}, wacc1 = {};
  float den = 0.f;

  auto stage = [&](int kt, int s) {
#pragma unroll
    for (int r = 0; r < 4; ++r) {
      int idx = r * 128 + tid;
      int row = idx >> 3, cc = idx & 7;
      int cs = cc ^ (row & 7);
      gload_lds16(Qg + (size_t)(kt * 64 + row) * 64 + cs * 8,
                  &Ks[s][(r * 128 + wid * 64) * 8]);
      gload_lds16(Vg + (size_t)row * Nc + kt * 64 + cs * 8,
                  &Vs[s][(r * 128 + wid * 64) * 8]);
    }
    if (wid == 0) gload_lds4(ekg + kt * 64 + lane, &ekLds[s][0]);
  };

  stage(0, 0);
  __syncthreads();

  for (int kt = 0; kt < Nc / 64; ++kt) {
    const int cur = kt & 1;
    if (kt + 1 < Nc / 64) stage(kt + 1, cur ^ 1);

#pragma unroll
    for (int kg = 0; kg < 2; ++kg) {
      // K fragments (A-operand: row=key=kg*32+lo, k = kk*16 + hi*8 + t)
      short8 kf[4];
#pragma unroll
      for (int kk = 0; kk < 4; ++kk) {
        int row = kg * 32 + lo;
        int c = (kk * 2 + hi) ^ (row & 7);
        kf[kk] = *reinterpret_cast<const short8*>(&Ks[cur][row * 64 + c * 8]);
      }
      f32x16 sacc = {};
      __builtin_amdgcn_s_setprio(1);
#pragma unroll
      for (int kk = 0; kk < 4; ++kk)
        sacc = __builtin_amdgcn_mfma_f32_32x32x16_bf16(kf[kk], qf[kk], sacc, 0, 0, 0);
      __builtin_amdgcn_s_setprio(0);

      // g = exp2(2log2e * s - q2l); den += g * ek; pack to bf16 pairs
      float gv[16];
      unsigned pk[8];
#pragma unroll
      for (int q = 0; q < 4; ++q) {
        float4 ekq = *reinterpret_cast<const float4*>(&ekLds[cur][kg * 32 + q * 8 + hi * 4]);
#pragma unroll
        for (int rr = 0; rr < 4; ++rr) {
          int reg = q * 4 + rr;
          float l2 = fmaf(sacc[reg], 2.0f * LOG2E, -q2l_r);
          float g = fexp2(l2);
          gv[reg] = g;
          float ekv = (rr == 0) ? ekq.x : (rr == 1) ? ekq.y : (rr == 2) ? ekq.z : ekq.w;
          den = fmaf(g, ekv, den);
        }
        pk[q * 2]     = cvt_pk_bf16(gv[q * 4 + 0], gv[q * 4 + 1]);
        pk[q * 2 + 1] = cvt_pk_bf16(gv[q * 4 + 2], gv[q * 4 + 3]);
      }

      // PV per 16-key sub-window (kkl): build A-frag via 2 permlane32_swap.
      // permlane32_swap(a,b) -> {[a_lo,b_lo], [a_hi,b_hi]} (lane halves).
      // Lane needs keys hi*8..hi*8+7: u0=[x_lo,y_lo] u1=[w_lo,z_lo] u2=[x_hi,y_hi] u3=[w_hi,z_hi].
#pragma unroll
      for (int kkl = 0; kkl < 2; ++kkl) {
        unsigned x = pk[4 * kkl + 0];   // keys 16kkl+{0,1}+4hi
        unsigned w = pk[4 * kkl + 1];   // keys 16kkl+{2,3}+4hi
        unsigned y = pk[4 * kkl + 2];   // keys 16kkl+8+{0,1}+4hi
        unsigned z = pk[4 * kkl + 3];   // keys 16kkl+8+{2,3}+4hi
        uint2v r0 = __builtin_amdgcn_permlane32_swap(x, y, false, false);
        uint2v r1 = __builtin_amdgcn_permlane32_swap(w, z, false, false);
        uint4v u; u[0] = r0[0]; u[1] = r1[0]; u[2] = r0[1]; u[3] = r1[1];
        short8 pa = __builtin_bit_cast(short8, u);

        __builtin_amdgcn_s_setprio(1);
#pragma unroll
        for (int dt = 0; dt < 2; ++dt) {
          int row = dt * 32 + lo;
          int c = (kg * 4 + kkl * 2 + hi) ^ (row & 7);
          short8 vfr = *reinterpret_cast<const short8*>(&Vs[cur][row * 64 + c * 8]);
          if (dt == 0)
            wacc0 = __builtin_amdgcn_mfma_f32_32x32x16_bf16(pa, vfr, wacc0, 0, 0, 0);
          else
            wacc1 = __builtin_amdgcn_mfma_f32_32x32x16_bf16(pa, vfr, wacc1, 0, 0, 0);
        }
        __builtin_amdgcn_s_setprio(0);
      }
    }
    __syncthreads();
  }

  // den: both hi-halves hold partials for qrow=lo -> combine, invert, exchange via LDS
  den += __shfl_xor(den, 32);
  float inv = 1.f / den;
  if (hi == 0) invLds[wid][lo] = inv;
  __builtin_amdgcn_s_waitcnt(0);  // wave-internal LDS ordering

  float4 iq[4];
#pragma unroll
  for (int q = 0; q < 4; ++q)
    iq[q] = *reinterpret_cast<const float4*>(&invLds[wid][q * 8 + hi * 4]);

#pragma unroll
  for (int dt = 0; dt < 2; ++dt) {
#pragma unroll
    for (int reg = 0; reg < 16; ++reg) {
      float val = (dt == 0 ? wacc0[reg] : wacc1[reg]);
      float iv = (reg & 3) == 0 ? iq[reg >> 2].x : (reg & 3) == 1 ? iq[reg >> 2].y
               : (reg & 3) == 2 ? iq[reg >> 2].z : iq[reg >> 2].w;
      int nn = qbase + (reg & 3) + 8 * (reg >> 2) + 4 * hi;
      wout[((size_t)b * Nc + nn) * 1024 + h * 64 + dt * 32 + lo] = f2bf(val * iv);
    }
  }
}

extern "C" void kernel_launch(void* const* d_in, const int* in_sizes, int n_in,
                              void* d_out, int out_size, void* d_ws, size_t ws_size,
                              hipStream_t stream) {
  const float* x    = (const float*)d_in[0];
  const float* Wqk  = (const float*)d_in[1];
  const float* Wv   = (const float*)d_in[2];
  const float* Wout = (const float*)d_in[3];
  float* out = (float*)d_out;
  char* ws = (char*)d_ws;

  unsigned short* x_bf    = (unsigned short*)(ws + 0);          //  8 MB
  unsigned short* wqk_bf  = (unsigned short*)(ws + 8388608);    //  2 MB
  unsigned short* wv_bf   = (unsigned short*)(ws + 10485760);   //  2 MB
  unsigned short* wout_bf = (unsigned short*)(ws + 12582912);   //  2 MB
  unsigned short* qk_buf  = (unsigned short*)(ws + 14680064);   //  8 MB (B,H,N,d)
  unsigned short* vt_buf  = (unsigned short*)(ws + 23068672);   //  8 MB (B,H,d,N) ek-scaled
  float*          q2l_buf = (float*)        (ws + 31457280);    // 256 KB
  float*          ek_buf  = (float*)        (ws + 31719424);    // 256 KB
  unsigned short* w_buf   = (unsigned short*)(ws + 31981568);   //  8 MB (B,N,D)

  cvt_bf16<<<2048, 256, 0, stream>>>(x, x_bf, 524288);
  cvt_bf16<<<512, 256, 0, stream>>>(Wqk, wqk_bf, 131072);
  cvt_bf16<<<512, 256, 0, stream>>>(Wv, wv_bf, 131072);
  cvt_bf16<<<512, 256, 0, stream>>>(Wout, wout_bf, 131072);

  gemm_bt<0><<<256, 256, 0, stream>>>(x_bf, wqk_bf, (void*)qk_buf, nullptr);

  q2ek_kernel<<<1024, 256, 0, stream>>>(qk_buf, q2l_buf, ek_buf);

  gemm_bt<2><<<256, 256, 0, stream>>>(x_bf, wv_bf, (void*)vt_buf, ek_buf);

  attn_kernel<<<1024, 128, 0, stream>>>(qk_buf, vt_buf, q2l_buf, ek_buf, w_buf);

  gemm_bt<1><<<256, 256, 0, stream>>>(w_buf, wout_bf, (void*)out, nullptr);
}

// Round 5
// 137.456 us; speedup vs baseline: 1.3845x; 1.0321x over previous
//
#include <hip/hip_runtime.h>

typedef __attribute__((ext_vector_type(8))) short short8;
typedef __attribute__((ext_vector_type(4))) float f32x4;
typedef __attribute__((ext_vector_type(16))) float f32x16;
typedef __attribute__((ext_vector_type(4))) unsigned short ushort4v;
typedef __attribute__((ext_vector_type(4))) unsigned int uint4v;
typedef __attribute__((ext_vector_type(2))) unsigned int uint2v;

constexpr int Nc = 2048, Kc = 1024;
constexpr float LOG2E = 1.4426950408889634f;

__device__ inline unsigned short f2bf(float f) {
  unsigned u = __builtin_bit_cast(unsigned, f);
  u = u + 0x7FFFu + ((u >> 16) & 1u);
  return (unsigned short)(u >> 16);
}
__device__ inline float bf2f(unsigned short h) {
  unsigned u = ((unsigned)h) << 16;
  return __builtin_bit_cast(float, u);
}
__device__ inline float fexp2(float x) {
  float r;
  asm("v_exp_f32 %0, %1" : "=v"(r) : "v"(x));
  return r;
}
__device__ inline unsigned cvt_pk_bf16(float lo, float hi) {
  unsigned r;
  asm("v_cvt_pk_bf16_f32 %0, %1, %2" : "=v"(r) : "v"(lo), "v"(hi));
  return r;
}

__device__ inline void gload_lds16(const void* g, void* l) {
  __builtin_amdgcn_global_load_lds(
      (const __attribute__((address_space(1))) unsigned int*)g,
      (__attribute__((address_space(3))) unsigned int*)l, 16, 0, 0);
}

// ---------------- fp32 -> bf16 convert (8 elems/thread) ----------------
__global__ __launch_bounds__(256) void cvt_bf16(const float* __restrict__ src,
                                                unsigned short* __restrict__ dst, int n8) {
  int i = blockIdx.x * 256 + threadIdx.x;
  if (i >= n8) return;
  const float4* s = reinterpret_cast<const float4*>(src) + 2 * (size_t)i;
  float4 a = s[0], b = s[1];
  short8 o;
  o[0] = (short)f2bf(a.x); o[1] = (short)f2bf(a.y); o[2] = (short)f2bf(a.z); o[3] = (short)f2bf(a.w);
  o[4] = (short)f2bf(b.x); o[5] = (short)f2bf(b.y); o[6] = (short)f2bf(b.z); o[7] = (short)f2bf(b.w);
  *reinterpret_cast<short8*>(dst + (size_t)i * 8) = o;
}

// ---------------- bf16 GEMM: C[m][e] = sum_k A[m][k] * W[e][k] ----------------
// MODE 0: bf16 scatter to (B,H,N,d). MODE 1: fp32 row-major.
// MODE 2: bf16 scatter to (B,H,d,N), scaled by bf16 ek[b,h,n] (V' = ek * V).
template<int MODE>
__global__ __launch_bounds__(256) void gemm_bt(const unsigned short* __restrict__ A,
                                               const unsigned short* __restrict__ W,
                                               void* __restrict__ Cout,
                                               const unsigned short* __restrict__ ekbf) {
  __shared__ unsigned short As[128 * 64];
  __shared__ unsigned short Bs[128 * 64];
  const int tid = threadIdx.x;
  const int bm = blockIdx.x & 31;
  const int bn = blockIdx.x >> 5;
  const int lane = tid & 63, wid = tid >> 6;
  const int wr = wid >> 1, wc = wid & 1;
  const int lr = lane & 15, lg = lane >> 4;

  f32x4 acc[4][4] = {};

  const unsigned short* Abase = A + (size_t)bm * 128 * Kc;
  const unsigned short* Wbase = W + (size_t)bn * 128 * Kc;

  for (int kt = 0; kt < Kc / 64; ++kt) {
    __syncthreads();
#pragma unroll
    for (int r = 0; r < 4; ++r) {
      int idx = r * 256 + tid;
      int row = idx >> 3, cc = idx & 7;
      int cs = cc ^ (row & 7);
      unsigned short* dstA = &As[(r * 256 + wid * 64) * 8];
      unsigned short* dstB = &Bs[(r * 256 + wid * 64) * 8];
      gload_lds16(Abase + (size_t)row * Kc + kt * 64 + cs * 8, dstA);
      gload_lds16(Wbase + (size_t)row * Kc + kt * 64 + cs * 8, dstB);
    }
    __syncthreads();

    short8 af[4][2], bfv[4][2];
#pragma unroll
    for (int m = 0; m < 4; ++m) {
      int row = wr * 64 + m * 16 + lr;
#pragma unroll
      for (int kh = 0; kh < 2; ++kh) {
        int cs = (kh * 4 + lg) ^ (row & 7);
        af[m][kh] = *reinterpret_cast<const short8*>(&As[row * 64 + cs * 8]);
      }
    }
#pragma unroll
    for (int n = 0; n < 4; ++n) {
      int row = wc * 64 + n * 16 + lr;
#pragma unroll
      for (int kh = 0; kh < 2; ++kh) {
        int cs = (kh * 4 + lg) ^ (row & 7);
        bfv[n][kh] = *reinterpret_cast<const short8*>(&Bs[row * 64 + cs * 8]);
      }
    }
#pragma unroll
    for (int kh = 0; kh < 2; ++kh)
#pragma unroll
      for (int m = 0; m < 4; ++m)
#pragma unroll
        for (int n = 0; n < 4; ++n)
          acc[m][n] = __builtin_amdgcn_mfma_f32_16x16x32_bf16(af[m][kh], bfv[n][kh], acc[m][n], 0, 0, 0);
  }

#pragma unroll
  for (int m = 0; m < 4; ++m) {
#pragma unroll
    for (int n = 0; n < 4; ++n) {
      int grow0 = bm * 128 + wr * 64 + m * 16 + lg * 4;
      int gcol = bn * 128 + wc * 64 + n * 16 + lr;
      if constexpr (MODE == 2) {
        int b = grow0 >> 11, nn0 = grow0 & 2047;
        int h = gcol >> 6, dd = gcol & 63;
        ushort4v ekq = *reinterpret_cast<const ushort4v*>(&ekbf[((size_t)(b * 16 + h)) * 2048 + nn0]);
        ushort4v pk;
        pk[0] = f2bf(acc[m][n][0] * bf2f(ekq[0]));
        pk[1] = f2bf(acc[m][n][1] * bf2f(ekq[1]));
        pk[2] = f2bf(acc[m][n][2] * bf2f(ekq[2]));
        pk[3] = f2bf(acc[m][n][3] * bf2f(ekq[3]));
        unsigned short* Dst = (unsigned short*)Cout;
        *reinterpret_cast<ushort4v*>(&Dst[(((size_t)(b * 16 + h)) * 64 + dd) * 2048 + nn0]) = pk;
      } else {
#pragma unroll
        for (int r = 0; r < 4; ++r) {
          int grow = grow0 + r;
          float val = acc[m][n][r];
          if constexpr (MODE == 0) {
            unsigned short* Dst = (unsigned short*)Cout;
            int b = grow >> 11, nn = grow & 2047;
            int h = gcol >> 6, dd = gcol & 63;
            Dst[(((size_t)(b * 16 + h)) * 2048 + nn) * 64 + dd] = f2bf(val);
          } else {
            float* Dst = (float*)Cout;
            Dst[(size_t)grow * 1024 + gcol] = val;
          }
        }
      }
    }
  }
}

// -- q2l[row] = log2e*||qk_row||^2 ; ekbf[row] = bf16(exp(-||qk_row||^2)) --
__global__ __launch_bounds__(256) void q2ek_kernel(const unsigned short* __restrict__ qk,
                                                   float* __restrict__ q2l,
                                                   unsigned short* __restrict__ ekbf) {
  int t = blockIdx.x * 256 + threadIdx.x;
  int row = t >> 2, q = t & 3;
  const short8* p = reinterpret_cast<const short8*>(qk + (size_t)row * 64 + q * 16);
  short8 v0 = p[0], v1 = p[1];
  float s = 0.f;
#pragma unroll
  for (int i = 0; i < 8; ++i) {
    float f0 = bf2f((unsigned short)v0[i]);
    float f1 = bf2f((unsigned short)v1[i]);
    s += f0 * f0 + f1 * f1;
  }
  s += __shfl_xor(s, 1);
  s += __shfl_xor(s, 2);
  if (q == 0) {
    q2l[row] = s * LOG2E;
    ekbf[row] = f2bf(__expf(-s));
  }
}

// ---------------- fused distance-attention ----------------
// 512 blocks x 256 threads (4 waves, 32 q-rows each). 64-key tiles, dbuf LDS.
// S^T = mfma_32x32x16(K, Q); g = exp2(2log2e*s - q2l) in-register;
// P-frags via cvt_pk + permlane32_swap; V pre-scaled by ek;
// den via MFMA: dacc = mfma(pa, ek_frag) -> row-aligned with wacc, no reduce.
__global__ __launch_bounds__(256) void attn_kernel(const unsigned short* __restrict__ qk,
                                                   const unsigned short* __restrict__ vt,
                                                   const float* __restrict__ q2lg_,
                                                   const unsigned short* __restrict__ ekbf_,
                                                   unsigned short* __restrict__ wout) {
  __shared__ unsigned short Ks[2][64 * 64];
  __shared__ unsigned short Vs[2][64 * 64];
  __shared__ unsigned short ekL[2][64];

  const int tid = threadIdx.x;
  // XCD-chunked swizzle (512 % 8 == 0): contiguous orig per XCD.
  const int orig = (blockIdx.x & 7) * 64 + (blockIdx.x >> 3);
  const int bh = orig >> 4;          // 0..31
  const int qt = orig & 15;          // 16 q-tiles of 128 rows
  const int b = bh >> 4, h = bh & 15;
  const unsigned short* Qg = qk + (size_t)bh * Nc * 64;
  const unsigned short* Vg = vt + (size_t)bh * 64 * Nc;
  const float* q2lg = q2lg_ + (size_t)bh * Nc;
  const unsigned short* ekg = ekbf_ + (size_t)bh * Nc;
  const int lane = tid & 63, wid = tid >> 6;
  const int lo = lane & 31, hi = lane >> 5;

  const int qbase = qt * 128 + wid * 32;

  // Q fragments (B-operand of 32x32x16: col=qrow=lo, k = kk*16 + hi*8 + t)
  short8 qf[4];
#pragma unroll
  for (int kk = 0; kk < 4; ++kk)
    qf[kk] = *reinterpret_cast<const short8*>(
        Qg + (size_t)(qbase + lo) * 64 + kk * 16 + hi * 8);

  const float q2l_r = q2lg[qbase + lo];

  f32x16 wacc0 = {}, wacc1 = {}, dacc = {};

  auto stage = [&](int kt, int s) {
#pragma unroll
    for (int r = 0; r < 2; ++r) {
      int idx = r * 256 + tid;
      int row = idx >> 3, cc = idx & 7;
      int cs = cc ^ (row & 7);
      gload_lds16(Qg + (size_t)(kt * 64 + row) * 64 + cs * 8,
                  &Ks[s][(r * 256 + wid * 64) * 8]);
      gload_lds16(Vg + (size_t)row * Nc + kt * 64 + cs * 8,
                  &Vs[s][(r * 256 + wid * 64) * 8]);
    }
    if (tid < 8) gload_lds16(ekg + kt * 64 + tid * 8, &ekL[s][0]);
  };

  stage(0, 0);
  __syncthreads();

  for (int kt = 0; kt < Nc / 64; ++kt) {
    const int cur = kt & 1;
    if (kt + 1 < Nc / 64) stage(kt + 1, cur ^ 1);

#pragma unroll
    for (int kg = 0; kg < 2; ++kg) {
      // K fragments (A-operand: row=key=kg*32+lo, k = kk*16 + hi*8 + t)
      short8 kf[4];
#pragma unroll
      for (int kk = 0; kk < 4; ++kk) {
        int row = kg * 32 + lo;
        int c = (kk * 2 + hi) ^ (row & 7);
        kf[kk] = *reinterpret_cast<const short8*>(&Ks[cur][row * 64 + c * 8]);
      }
      f32x16 sacc = {};
      __builtin_amdgcn_s_setprio(1);
#pragma unroll
      for (int kk = 0; kk < 4; ++kk)
        sacc = __builtin_amdgcn_mfma_f32_32x32x16_bf16(kf[kk], qf[kk], sacc, 0, 0, 0);
      __builtin_amdgcn_s_setprio(0);

      // g = exp2(2log2e * s - q2l); pack to bf16 pairs (no per-elem den fma)
      float gv[16];
      unsigned pk[8];
#pragma unroll
      for (int q = 0; q < 4; ++q) {
#pragma unroll
        for (int rr = 0; rr < 4; ++rr) {
          int reg = q * 4 + rr;
          float l2 = fmaf(sacc[reg], 2.0f * LOG2E, -q2l_r);
          gv[reg] = fexp2(l2);
        }
        pk[q * 2]     = cvt_pk_bf16(gv[q * 4 + 0], gv[q * 4 + 1]);
        pk[q * 2 + 1] = cvt_pk_bf16(gv[q * 4 + 2], gv[q * 4 + 3]);
      }

      // PV + den per 16-key sub-window (kkl).
      // permlane32_swap(a,b) -> {[a_lo,b_lo], [a_hi,b_hi]} (lane halves).
#pragma unroll
      for (int kkl = 0; kkl < 2; ++kkl) {
        unsigned x = pk[4 * kkl + 0];
        unsigned w = pk[4 * kkl + 1];
        unsigned y = pk[4 * kkl + 2];
        unsigned z = pk[4 * kkl + 3];
        uint2v r0 = __builtin_amdgcn_permlane32_swap(x, y, false, false);
        uint2v r1 = __builtin_amdgcn_permlane32_swap(w, z, false, false);
        uint4v u; u[0] = r0[0]; u[1] = r1[0]; u[2] = r0[1]; u[3] = r1[1];
        short8 pa = __builtin_bit_cast(short8, u);

        // ek B-fragment: broadcast read, all lanes of a hi-half same addr
        short8 ekf = *reinterpret_cast<const short8*>(&ekL[cur][kg * 32 + kkl * 16 + hi * 8]);

        __builtin_amdgcn_s_setprio(1);
        dacc = __builtin_amdgcn_mfma_f32_32x32x16_bf16(pa, ekf, dacc, 0, 0, 0);
#pragma unroll
        for (int dt = 0; dt < 2; ++dt) {
          int row = dt * 32 + lo;
          int c = (kg * 4 + kkl * 2 + hi) ^ (row & 7);
          short8 vfr = *reinterpret_cast<const short8*>(&Vs[cur][row * 64 + c * 8]);
          if (dt == 0)
            wacc0 = __builtin_amdgcn_mfma_f32_32x32x16_bf16(pa, vfr, wacc0, 0, 0, 0);
          else
            wacc1 = __builtin_amdgcn_mfma_f32_32x32x16_bf16(pa, vfr, wacc1, 0, 0, 0);
        }
        __builtin_amdgcn_s_setprio(0);
      }
    }
    __syncthreads();
  }

  // dacc rows align with wacc rows: inv per reg, no cross-lane exchange.
#pragma unroll
  for (int reg = 0; reg < 16; ++reg) {
    float iv = __builtin_amdgcn_rcpf(dacc[reg]);
    int nn = qbase + (reg & 3) + 8 * (reg >> 2) + 4 * hi;
    size_t base = ((size_t)b * Nc + nn) * 1024 + h * 64 + lo;
    wout[base]      = f2bf(wacc0[reg] * iv);
    wout[base + 32] = f2bf(wacc1[reg] * iv);
  }
}

extern "C" void kernel_launch(void* const* d_in, const int* in_sizes, int n_in,
                              void* d_out, int out_size, void* d_ws, size_t ws_size,
                              hipStream_t stream) {
  const float* x    = (const float*)d_in[0];
  const float* Wqk  = (const float*)d_in[1];
  const float* Wv   = (const float*)d_in[2];
  const float* Wout = (const float*)d_in[3];
  float* out = (float*)d_out;
  char* ws = (char*)d_ws;

  unsigned short* x_bf    = (unsigned short*)(ws + 0);          //  8 MB
  unsigned short* wqk_bf  = (unsigned short*)(ws + 8388608);    //  2 MB
  unsigned short* wv_bf   = (unsigned short*)(ws + 10485760);   //  2 MB
  unsigned short* wout_bf = (unsigned short*)(ws + 12582912);   //  2 MB
  unsigned short* qk_buf  = (unsigned short*)(ws + 14680064);   //  8 MB (B,H,N,d)
  unsigned short* vt_buf  = (unsigned short*)(ws + 23068672);   //  8 MB (B,H,d,N) ek-scaled
  float*          q2l_buf = (float*)        (ws + 31457280);    // 256 KB
  unsigned short* ekbf_buf= (unsigned short*)(ws + 31719424);   // 128 KB (bf16 ek)
  unsigned short* w_buf   = (unsigned short*)(ws + 31981568);   //  8 MB (B,N,D)

  cvt_bf16<<<2048, 256, 0, stream>>>(x, x_bf, 524288);
  cvt_bf16<<<512, 256, 0, stream>>>(Wqk, wqk_bf, 131072);
  cvt_bf16<<<512, 256, 0, stream>>>(Wv, wv_bf, 131072);
  cvt_bf16<<<512, 256, 0, stream>>>(Wout, wout_bf, 131072);

  gemm_bt<0><<<256, 256, 0, stream>>>(x_bf, wqk_bf, (void*)qk_buf, nullptr);

  q2ek_kernel<<<1024, 256, 0, stream>>>(qk_buf, q2l_buf, ekbf_buf);

  gemm_bt<2><<<256, 256, 0, stream>>>(x_bf, wv_bf, (void*)vt_buf, ekbf_buf);

  attn_kernel<<<512, 256, 0, stream>>>(qk_buf, vt_buf, q2l_buf, ekbf_buf, w_buf);

  gemm_bt<1><<<256, 256, 0, stream>>>(w_buf, wout_bf, (void*)out, nullptr);
}

// Round 6
// 126.779 us; speedup vs baseline: 1.5011x; 1.0842x over previous
//
#include <hip/hip_runtime.h>

typedef __attribute__((ext_vector_type(8))) short short8;
typedef __attribute__((ext_vector_type(4))) float f32x4;
typedef __attribute__((ext_vector_type(16))) float f32x16;
typedef __attribute__((ext_vector_type(4))) unsigned short ushort4v;
typedef __attribute__((ext_vector_type(4))) unsigned int uint4v;
typedef __attribute__((ext_vector_type(2))) unsigned int uint2v;

constexpr int Nc = 2048, Kc = 1024;
constexpr float LOG2E = 1.4426950408889634f;

__device__ inline unsigned short f2bf(float f) {
  unsigned u = __builtin_bit_cast(unsigned, f);
  u = u + 0x7FFFu + ((u >> 16) & 1u);
  return (unsigned short)(u >> 16);
}
__device__ inline float bf2f(unsigned short h) {
  unsigned u = ((unsigned)h) << 16;
  return __builtin_bit_cast(float, u);
}
__device__ inline float fexp2(float x) {
  float r;
  asm("v_exp_f32 %0, %1" : "=v"(r) : "v"(x));
  return r;
}
__device__ inline unsigned cvt_pk_bf16(float lo, float hi) {
  unsigned r;
  asm("v_cvt_pk_bf16_f32 %0, %1, %2" : "=v"(r) : "v"(lo), "v"(hi));
  return r;
}

__device__ inline void gload_lds16(const void* g, void* l) {
  __builtin_amdgcn_global_load_lds(
      (const __attribute__((address_space(1))) unsigned int*)g,
      (__attribute__((address_space(3))) unsigned int*)l, 16, 0, 0);
}

// ---------------- fp32 -> bf16 convert (8 elems/thread) ----------------
__global__ __launch_bounds__(256) void cvt_bf16(const float* __restrict__ src,
                                                unsigned short* __restrict__ dst, int n8) {
  int i = blockIdx.x * 256 + threadIdx.x;
  if (i >= n8) return;
  const float4* s = reinterpret_cast<const float4*>(src) + 2 * (size_t)i;
  float4 a = s[0], b = s[1];
  short8 o;
  o[0] = (short)f2bf(a.x); o[1] = (short)f2bf(a.y); o[2] = (short)f2bf(a.z); o[3] = (short)f2bf(a.w);
  o[4] = (short)f2bf(b.x); o[5] = (short)f2bf(b.y); o[6] = (short)f2bf(b.z); o[7] = (short)f2bf(b.w);
  *reinterpret_cast<short8*>(dst + (size_t)i * 8) = o;
}

// ------- merged projection GEMM: qk = x@Wqk^T (scatter B,H,N,d), v^T = x@Wv^T (scatter B,H,d,N) -------
// 128x128 tiles; grid 32 x 16 = 512 blocks (bn<8 -> qk, bn>=8 -> vt).
__global__ __launch_bounds__(256) void gemm_proj(const unsigned short* __restrict__ A,
                                                 const unsigned short* __restrict__ Wqk,
                                                 const unsigned short* __restrict__ Wv,
                                                 unsigned short* __restrict__ qk_out,
                                                 unsigned short* __restrict__ vt_out) {
  __shared__ unsigned short As[128 * 64];
  __shared__ unsigned short Bs[128 * 64];
  const int tid = threadIdx.x;
  const int bm = blockIdx.x & 31;
  const int bn = blockIdx.x >> 5;      // 0..15
  const bool isV = bn >= 8;
  const int lane = tid & 63, wid = tid >> 6;
  const int wr = wid >> 1, wc = wid & 1;
  const int lr = lane & 15, lg = lane >> 4;

  f32x4 acc[4][4] = {};

  const unsigned short* Abase = A + (size_t)bm * 128 * Kc;
  const unsigned short* Wbase = (isV ? Wv + (size_t)(bn - 8) * 128 * Kc
                                     : Wqk + (size_t)bn * 128 * Kc);

  for (int kt = 0; kt < Kc / 64; ++kt) {
    __syncthreads();
#pragma unroll
    for (int r = 0; r < 4; ++r) {
      int idx = r * 256 + tid;
      int row = idx >> 3, cc = idx & 7;
      int cs = cc ^ (row & 7);
      gload_lds16(Abase + (size_t)row * Kc + kt * 64 + cs * 8, &As[(r * 256 + wid * 64) * 8]);
      gload_lds16(Wbase + (size_t)row * Kc + kt * 64 + cs * 8, &Bs[(r * 256 + wid * 64) * 8]);
    }
    __syncthreads();

    short8 af[4][2], bfv[4][2];
#pragma unroll
    for (int m = 0; m < 4; ++m) {
      int row = wr * 64 + m * 16 + lr;
#pragma unroll
      for (int kh = 0; kh < 2; ++kh) {
        int cs = (kh * 4 + lg) ^ (row & 7);
        af[m][kh] = *reinterpret_cast<const short8*>(&As[row * 64 + cs * 8]);
      }
    }
#pragma unroll
    for (int n = 0; n < 4; ++n) {
      int row = wc * 64 + n * 16 + lr;
#pragma unroll
      for (int kh = 0; kh < 2; ++kh) {
        int cs = (kh * 4 + lg) ^ (row & 7);
        bfv[n][kh] = *reinterpret_cast<const short8*>(&Bs[row * 64 + cs * 8]);
      }
    }
#pragma unroll
    for (int kh = 0; kh < 2; ++kh)
#pragma unroll
      for (int m = 0; m < 4; ++m)
#pragma unroll
        for (int n = 0; n < 4; ++n)
          acc[m][n] = __builtin_amdgcn_mfma_f32_16x16x32_bf16(af[m][kh], bfv[n][kh], acc[m][n], 0, 0, 0);
  }

#pragma unroll
  for (int m = 0; m < 4; ++m) {
#pragma unroll
    for (int n = 0; n < 4; ++n) {
      int grow0 = bm * 128 + wr * 64 + m * 16 + lg * 4;
      int b = grow0 >> 11, nn0 = grow0 & 2047;
      if (isV) {
        int gcol = (bn - 8) * 128 + wc * 64 + n * 16 + lr;
        int h = gcol >> 6, dd = gcol & 63;
        ushort4v pk;
#pragma unroll
        for (int r = 0; r < 4; ++r) pk[r] = f2bf(acc[m][n][r]);
        *reinterpret_cast<ushort4v*>(&vt_out[(((size_t)(b * 16 + h)) * 64 + dd) * 2048 + nn0]) = pk;
      } else {
        int gcol = bn * 128 + wc * 64 + n * 16 + lr;
        int h = gcol >> 6, dd = gcol & 63;
#pragma unroll
        for (int r = 0; r < 4; ++r)
          qk_out[(((size_t)(b * 16 + h)) * 2048 + nn0 + r) * 64 + dd] = f2bf(acc[m][n][r]);
      }
    }
  }
}

// ------- output GEMM: out[m][e] = sum_k w[m][k] * Wout[e][k], fp32 out -------
// 128x64 tiles; grid 32 x 16 = 512 blocks.
__global__ __launch_bounds__(256) void gemm_out(const unsigned short* __restrict__ A,
                                                const unsigned short* __restrict__ W,
                                                float* __restrict__ out) {
  __shared__ unsigned short As[128 * 64];
  __shared__ unsigned short Bs[64 * 64];
  const int tid = threadIdx.x;
  const int bm = blockIdx.x & 31;
  const int bn = blockIdx.x >> 5;      // 0..15 (64-col tiles)
  const int lane = tid & 63, wid = tid >> 6;
  const int wr = wid >> 1, wc = wid & 1;
  const int lr = lane & 15, lg = lane >> 4;

  f32x4 acc[4][2] = {};

  const unsigned short* Abase = A + (size_t)bm * 128 * Kc;
  const unsigned short* Wbase = W + (size_t)bn * 64 * Kc;

  for (int kt = 0; kt < Kc / 64; ++kt) {
    __syncthreads();
#pragma unroll
    for (int r = 0; r < 4; ++r) {
      int idx = r * 256 + tid;
      int row = idx >> 3, cc = idx & 7;
      int cs = cc ^ (row & 7);
      gload_lds16(Abase + (size_t)row * Kc + kt * 64 + cs * 8, &As[(r * 256 + wid * 64) * 8]);
    }
#pragma unroll
    for (int r = 0; r < 2; ++r) {
      int idx = r * 256 + tid;
      int row = idx >> 3, cc = idx & 7;
      int cs = cc ^ (row & 7);
      gload_lds16(Wbase + (size_t)row * Kc + kt * 64 + cs * 8, &Bs[(r * 256 + wid * 64) * 8]);
    }
    __syncthreads();

    short8 af[4][2], bfv[2][2];
#pragma unroll
    for (int m = 0; m < 4; ++m) {
      int row = wr * 64 + m * 16 + lr;
#pragma unroll
      for (int kh = 0; kh < 2; ++kh) {
        int cs = (kh * 4 + lg) ^ (row & 7);
        af[m][kh] = *reinterpret_cast<const short8*>(&As[row * 64 + cs * 8]);
      }
    }
#pragma unroll
    for (int n = 0; n < 2; ++n) {
      int row = wc * 32 + n * 16 + lr;
#pragma unroll
      for (int kh = 0; kh < 2; ++kh) {
        int cs = (kh * 4 + lg) ^ (row & 7);
        bfv[n][kh] = *reinterpret_cast<const short8*>(&Bs[row * 64 + cs * 8]);
      }
    }
#pragma unroll
    for (int kh = 0; kh < 2; ++kh)
#pragma unroll
      for (int m = 0; m < 4; ++m)
#pragma unroll
        for (int n = 0; n < 2; ++n)
          acc[m][n] = __builtin_amdgcn_mfma_f32_16x16x32_bf16(af[m][kh], bfv[n][kh], acc[m][n], 0, 0, 0);
  }

#pragma unroll
  for (int m = 0; m < 4; ++m)
#pragma unroll
    for (int n = 0; n < 2; ++n)
#pragma unroll
      for (int r = 0; r < 4; ++r) {
        int grow = bm * 128 + wr * 64 + m * 16 + lg * 4 + r;
        int gcol = bn * 64 + wc * 32 + n * 16 + lr;
        out[(size_t)grow * 1024 + gcol] = acc[m][n][r];
      }
}

// -------- q2l[row] = log2e * ||qk_row||^2 (rows = B*H*N) --------
__global__ __launch_bounds__(256) void q2_kernel(const unsigned short* __restrict__ qk,
                                                 float* __restrict__ q2l) {
  int t = blockIdx.x * 256 + threadIdx.x;
  int row = t >> 2, q = t & 3;
  const short8* p = reinterpret_cast<const short8*>(qk + (size_t)row * 64 + q * 16);
  short8 v0 = p[0], v1 = p[1];
  float s = 0.f;
#pragma unroll
  for (int i = 0; i < 8; ++i) {
    float f0 = bf2f((unsigned short)v0[i]);
    float f1 = bf2f((unsigned short)v1[i]);
    s += f0 * f0 + f1 * f1;
  }
  s += __shfl_xor(s, 1);
  s += __shfl_xor(s, 2);
  if (q == 0) q2l[row] = s * LOG2E;
}

// ---------------- fused distance-attention ----------------
// p = exp2(2L*s - L*q2i - L*q2j) in (0,1]; den = mfma(pa, ones) (row-aligned
// with wacc, no reduce). PARTIAL: K-split x2 (grid 1024, 16 tiles each), f32
// num/den partials. FINAL: single pass (grid 512), divide + write bf16.
template<bool PARTIAL>
__global__ __launch_bounds__(256) void attn_kernel(const unsigned short* __restrict__ qk,
                                                   const unsigned short* __restrict__ vt,
                                                   const float* __restrict__ q2lg_,
                                                   unsigned short* __restrict__ wout,
                                                   float* __restrict__ numP,
                                                   float* __restrict__ denP) {
  __shared__ unsigned short Ks[2][64 * 64];
  __shared__ unsigned short Vs[2][64 * 64];
  __shared__ float q2L[2][64];

  const int tid = threadIdx.x;
  // XCD-chunked swizzle (grid % 8 == 0)
  const int chunk = PARTIAL ? 128 : 64;
  const int orig = (blockIdx.x & 7) * chunk + (blockIdx.x >> 3);
  const int half = PARTIAL ? (orig >> 9) : 0;
  const int rest = PARTIAL ? (orig & 511) : orig;
  const int bh = rest >> 4;          // 0..31
  const int qt = rest & 15;          // 16 q-tiles of 128 rows
  const int b = bh >> 4, h = bh & 15;
  const unsigned short* Qg = qk + (size_t)bh * Nc * 64;
  const unsigned short* Vg = vt + (size_t)bh * 64 * Nc;
  const float* q2lg = q2lg_ + (size_t)bh * Nc;
  const int lane = tid & 63, wid = tid >> 6;
  const int lo = lane & 31, hi = lane >> 5;

  const int qbase = qt * 128 + wid * 32;
  const int kt0 = half * 16;
  const int ktn = PARTIAL ? 16 : 32;

  // Q fragments (B-operand of 32x32x16: col=qrow=lo, k = kk*16 + hi*8 + t)
  short8 qf[4];
#pragma unroll
  for (int kk = 0; kk < 4; ++kk)
    qf[kk] = *reinterpret_cast<const short8*>(
        Qg + (size_t)(qbase + lo) * 64 + kk * 16 + hi * 8);

  const float q2l_r = q2lg[qbase + lo];

  // constant ones B-fragment for den-MFMA
  uint4v ou; ou[0] = 0x3F803F80u; ou[1] = 0x3F803F80u; ou[2] = 0x3F803F80u; ou[3] = 0x3F803F80u;
  const short8 ones = __builtin_bit_cast(short8, ou);

  f32x16 wacc0 = {}, wacc1 = {}, dacc = {};

  auto stage = [&](int kt, int s) {
#pragma unroll
    for (int r = 0; r < 2; ++r) {
      int idx = r * 256 + tid;
      int row = idx >> 3, cc = idx & 7;
      int cs = cc ^ (row & 7);
      gload_lds16(Qg + (size_t)(kt * 64 + row) * 64 + cs * 8,
                  &Ks[s][(r * 256 + wid * 64) * 8]);
      gload_lds16(Vg + (size_t)row * Nc + kt * 64 + cs * 8,
                  &Vs[s][(r * 256 + wid * 64) * 8]);
    }
    if (tid < 16) gload_lds16(q2lg + kt * 64 + tid * 4, &q2L[s][0]);
  };

  stage(kt0, 0);
  __syncthreads();

  for (int t = 0; t < ktn; ++t) {
    const int kt = kt0 + t;
    const int cur = t & 1;
    if (t + 1 < ktn) stage(kt + 1, cur ^ 1);

#pragma unroll
    for (int kg = 0; kg < 2; ++kg) {
      // K fragments (A-operand: row=key=kg*32+lo, k = kk*16 + hi*8 + t)
      short8 kf[4];
#pragma unroll
      for (int kk = 0; kk < 4; ++kk) {
        int row = kg * 32 + lo;
        int c = (kk * 2 + hi) ^ (row & 7);
        kf[kk] = *reinterpret_cast<const short8*>(&Ks[cur][row * 64 + c * 8]);
      }
      f32x16 sacc = {};
      __builtin_amdgcn_s_setprio(1);
#pragma unroll
      for (int kk = 0; kk < 4; ++kk)
        sacc = __builtin_amdgcn_mfma_f32_32x32x16_bf16(kf[kk], qf[kk], sacc, 0, 0, 0);
      __builtin_amdgcn_s_setprio(0);

      // p = exp2(2L*s - (L*q2_row + L*q2_key)); pack to bf16 pairs
      float gv[16];
      unsigned pk[8];
#pragma unroll
      for (int q = 0; q < 4; ++q) {
        float4 k2q = *reinterpret_cast<const float4*>(&q2L[cur][kg * 32 + q * 8 + hi * 4]);
#pragma unroll
        for (int rr = 0; rr < 4; ++rr) {
          int reg = q * 4 + rr;
          float c = q2l_r + ((rr == 0) ? k2q.x : (rr == 1) ? k2q.y : (rr == 2) ? k2q.z : k2q.w);
          gv[reg] = fexp2(fmaf(sacc[reg], 2.0f * LOG2E, -c));
        }
        pk[q * 2]     = cvt_pk_bf16(gv[q * 4 + 0], gv[q * 4 + 1]);
        pk[q * 2 + 1] = cvt_pk_bf16(gv[q * 4 + 2], gv[q * 4 + 3]);
      }

      // PV + den per 16-key sub-window.
      // permlane32_swap(a,b) -> {[a_lo,b_lo], [a_hi,b_hi]} (lane halves).
#pragma unroll
      for (int kkl = 0; kkl < 2; ++kkl) {
        unsigned x = pk[4 * kkl + 0];
        unsigned w = pk[4 * kkl + 1];
        unsigned y = pk[4 * kkl + 2];
        unsigned z = pk[4 * kkl + 3];
        uint2v r0 = __builtin_amdgcn_permlane32_swap(x, y, false, false);
        uint2v r1 = __builtin_amdgcn_permlane32_swap(w, z, false, false);
        uint4v u; u[0] = r0[0]; u[1] = r1[0]; u[2] = r0[1]; u[3] = r1[1];
        short8 pa = __builtin_bit_cast(short8, u);

        __builtin_amdgcn_s_setprio(1);
        dacc = __builtin_amdgcn_mfma_f32_32x32x16_bf16(pa, ones, dacc, 0, 0, 0);
#pragma unroll
        for (int dt = 0; dt < 2; ++dt) {
          int row = dt * 32 + lo;
          int c = (kg * 4 + kkl * 2 + hi) ^ (row & 7);
          short8 vfr = *reinterpret_cast<const short8*>(&Vs[cur][row * 64 + c * 8]);
          if (dt == 0)
            wacc0 = __builtin_amdgcn_mfma_f32_32x32x16_bf16(pa, vfr, wacc0, 0, 0, 0);
          else
            wacc1 = __builtin_amdgcn_mfma_f32_32x32x16_bf16(pa, vfr, wacc1, 0, 0, 0);
        }
        __builtin_amdgcn_s_setprio(0);
      }
    }
    __syncthreads();
  }

  if constexpr (PARTIAL) {
    float* numh = numP + (size_t)half * 65536 * 64;
    float* denh = denP + (size_t)half * 65536;
#pragma unroll
    for (int reg = 0; reg < 16; ++reg) {
      int nn = qbase + (reg & 3) + 8 * (reg >> 2) + 4 * hi;
      size_t row = (size_t)bh * Nc + nn;
      numh[row * 64 + lo]      = wacc0[reg];
      numh[row * 64 + 32 + lo] = wacc1[reg];
      if (lo == 0) denh[row] = dacc[reg];
    }
  } else {
#pragma unroll
    for (int reg = 0; reg < 16; ++reg) {
      float iv = __builtin_amdgcn_rcpf(dacc[reg]);
      int nn = qbase + (reg & 3) + 8 * (reg >> 2) + 4 * hi;
      size_t base = ((size_t)b * Nc + nn) * 1024 + h * 64 + lo;
      wout[base]      = f2bf(wacc0[reg] * iv);
      wout[base + 32] = f2bf(wacc1[reg] * iv);
    }
  }
}

// -------- combine halves: w = (num0+num1)/(den0+den1), scatter to (B,N,D) bf16 --------
__global__ __launch_bounds__(256) void combine_kernel(const float* __restrict__ numP,
                                                      const float* __restrict__ denP,
                                                      unsigned short* __restrict__ wout) {
  int gid = blockIdx.x * 256 + threadIdx.x;   // 524288 threads, 8 d-elems each
  int row = gid >> 3, d0 = (gid & 7) * 8;
  const float* n0 = numP + (size_t)row * 64 + d0;
  const float* n1 = numP + (size_t)65536 * 64 + (size_t)row * 64 + d0;
  float iv = 1.0f / (denP[row] + denP[65536 + row]);
  float4 a0 = *reinterpret_cast<const float4*>(n0);
  float4 a1 = *reinterpret_cast<const float4*>(n0 + 4);
  float4 b0 = *reinterpret_cast<const float4*>(n1);
  float4 b1 = *reinterpret_cast<const float4*>(n1 + 4);
  short8 o;
  o[0] = (short)f2bf((a0.x + b0.x) * iv);
  o[1] = (short)f2bf((a0.y + b0.y) * iv);
  o[2] = (short)f2bf((a0.z + b0.z) * iv);
  o[3] = (short)f2bf((a0.w + b0.w) * iv);
  o[4] = (short)f2bf((a1.x + b1.x) * iv);
  o[5] = (short)f2bf((a1.y + b1.y) * iv);
  o[6] = (short)f2bf((a1.z + b1.z) * iv);
  o[7] = (short)f2bf((a1.w + b1.w) * iv);
  int bh = row >> 11, nn = row & 2047;
  int b = bh >> 4, h = bh & 15;
  *reinterpret_cast<short8*>(&wout[((size_t)b * Nc + nn) * 1024 + h * 64 + d0]) = o;
}

extern "C" void kernel_launch(void* const* d_in, const int* in_sizes, int n_in,
                              void* d_out, int out_size, void* d_ws, size_t ws_size,
                              hipStream_t stream) {
  const float* x    = (const float*)d_in[0];
  const float* Wqk  = (const float*)d_in[1];
  const float* Wv   = (const float*)d_in[2];
  const float* Wout = (const float*)d_in[3];
  float* out = (float*)d_out;
  char* ws = (char*)d_ws;

  unsigned short* x_bf    = (unsigned short*)(ws + 0);          //  8 MB
  unsigned short* wqk_bf  = (unsigned short*)(ws + 8388608);    //  2 MB
  unsigned short* wv_bf   = (unsigned short*)(ws + 10485760);   //  2 MB
  unsigned short* wout_bf = (unsigned short*)(ws + 12582912);   //  2 MB
  unsigned short* qk_buf  = (unsigned short*)(ws + 14680064);   //  8 MB (B,H,N,d)
  unsigned short* vt_buf  = (unsigned short*)(ws + 23068672);   //  8 MB (B,H,d,N)
  float*          q2l_buf = (float*)        (ws + 31457280);    // 256 KB
  unsigned short* w_buf   = (unsigned short*)(ws + 31719424);   //  8 MB (B,N,D)
  float*          num_buf = (float*)        (ws + 40108032);    // 32 MB (2 halves)
  float*          den_buf = (float*)        (ws + 73662464);    // 512 KB (2 halves)
  const size_t need_split = 74186752;

  cvt_bf16<<<2048, 256, 0, stream>>>(x, x_bf, 524288);
  cvt_bf16<<<512, 256, 0, stream>>>(Wqk, wqk_bf, 131072);
  cvt_bf16<<<512, 256, 0, stream>>>(Wv, wv_bf, 131072);
  cvt_bf16<<<512, 256, 0, stream>>>(Wout, wout_bf, 131072);

  gemm_proj<<<512, 256, 0, stream>>>(x_bf, wqk_bf, wv_bf, qk_buf, vt_buf);

  q2_kernel<<<1024, 256, 0, stream>>>(qk_buf, q2l_buf);

  if (ws_size >= need_split) {
    attn_kernel<true><<<1024, 256, 0, stream>>>(qk_buf, vt_buf, q2l_buf, nullptr, num_buf, den_buf);
    combine_kernel<<<2048, 256, 0, stream>>>(num_buf, den_buf, w_buf);
  } else {
    attn_kernel<false><<<512, 256, 0, stream>>>(qk_buf, vt_buf, q2l_buf, w_buf, nullptr, nullptr);
  }

  gemm_out<<<512, 256, 0, stream>>>(w_buf, wout_bf, out);
}

// Round 7
// 120.644 us; speedup vs baseline: 1.5774x; 1.0509x over previous
//
#include <hip/hip_runtime.h>

typedef __attribute__((ext_vector_type(8))) short short8;
typedef __attribute__((ext_vector_type(4))) float f32x4;
typedef __attribute__((ext_vector_type(16))) float f32x16;
typedef __attribute__((ext_vector_type(4))) unsigned short ushort4v;
typedef __attribute__((ext_vector_type(4))) unsigned int uint4v;
typedef __attribute__((ext_vector_type(2))) unsigned int uint2v;

constexpr int Nc = 2048, Kc = 1024;
constexpr float LOG2E = 1.4426950408889634f;

__device__ inline unsigned short f2bf(float f) {
  unsigned u = __builtin_bit_cast(unsigned, f);
  u = u + 0x7FFFu + ((u >> 16) & 1u);
  return (unsigned short)(u >> 16);
}
__device__ inline float bf2f(unsigned short h) {
  unsigned u = ((unsigned)h) << 16;
  return __builtin_bit_cast(float, u);
}
__device__ inline float fexp2(float x) {
  float r;
  asm("v_exp_f32 %0, %1" : "=v"(r) : "v"(x));
  return r;
}
__device__ inline unsigned cvt_pk_bf16(float lo, float hi) {
  unsigned r;
  asm("v_cvt_pk_bf16_f32 %0, %1, %2" : "=v"(r) : "v"(lo), "v"(hi));
  return r;
}

__device__ inline void gload_lds16(const void* g, void* l) {
  __builtin_amdgcn_global_load_lds(
      (const __attribute__((address_space(1))) unsigned int*)g,
      (__attribute__((address_space(3))) unsigned int*)l, 16, 0, 0);
}

// ---------------- fp32 -> bf16 convert (8 elems/thread) ----------------
__global__ __launch_bounds__(256) void cvt_bf16(const float* __restrict__ src,
                                                unsigned short* __restrict__ dst, int n8) {
  int i = blockIdx.x * 256 + threadIdx.x;
  if (i >= n8) return;
  const float4* s = reinterpret_cast<const float4*>(src) + 2 * (size_t)i;
  float4 a = s[0], b = s[1];
  short8 o;
  o[0] = (short)f2bf(a.x); o[1] = (short)f2bf(a.y); o[2] = (short)f2bf(a.z); o[3] = (short)f2bf(a.w);
  o[4] = (short)f2bf(b.x); o[5] = (short)f2bf(b.y); o[6] = (short)f2bf(b.z); o[7] = (short)f2bf(b.w);
  *reinterpret_cast<short8*>(dst + (size_t)i * 8) = o;
}

// ------- merged projection GEMM: qk = x@Wqk^T (scatter B,H,N,d), v^T = x@Wv^T (scatter B,H,d,N) -------
__global__ __launch_bounds__(256) void gemm_proj(const unsigned short* __restrict__ A,
                                                 const unsigned short* __restrict__ Wqk,
                                                 const unsigned short* __restrict__ Wv,
                                                 unsigned short* __restrict__ qk_out,
                                                 unsigned short* __restrict__ vt_out) {
  __shared__ unsigned short As[128 * 64];
  __shared__ unsigned short Bs[128 * 64];
  const int tid = threadIdx.x;
  const int bm = blockIdx.x & 31;
  const int bn = blockIdx.x >> 5;      // 0..15
  const bool isV = bn >= 8;
  const int lane = tid & 63, wid = tid >> 6;
  const int wr = wid >> 1, wc = wid & 1;
  const int lr = lane & 15, lg = lane >> 4;

  f32x4 acc[4][4] = {};

  const unsigned short* Abase = A + (size_t)bm * 128 * Kc;
  const unsigned short* Wbase = (isV ? Wv + (size_t)(bn - 8) * 128 * Kc
                                     : Wqk + (size_t)bn * 128 * Kc);

  for (int kt = 0; kt < Kc / 64; ++kt) {
    __syncthreads();
#pragma unroll
    for (int r = 0; r < 4; ++r) {
      int idx = r * 256 + tid;
      int row = idx >> 3, cc = idx & 7;
      int cs = cc ^ (row & 7);
      gload_lds16(Abase + (size_t)row * Kc + kt * 64 + cs * 8, &As[(r * 256 + wid * 64) * 8]);
      gload_lds16(Wbase + (size_t)row * Kc + kt * 64 + cs * 8, &Bs[(r * 256 + wid * 64) * 8]);
    }
    __syncthreads();

    short8 af[4][2], bfv[4][2];
#pragma unroll
    for (int m = 0; m < 4; ++m) {
      int row = wr * 64 + m * 16 + lr;
#pragma unroll
      for (int kh = 0; kh < 2; ++kh) {
        int cs = (kh * 4 + lg) ^ (row & 7);
        af[m][kh] = *reinterpret_cast<const short8*>(&As[row * 64 + cs * 8]);
      }
    }
#pragma unroll
    for (int n = 0; n < 4; ++n) {
      int row = wc * 64 + n * 16 + lr;
#pragma unroll
      for (int kh = 0; kh < 2; ++kh) {
        int cs = (kh * 4 + lg) ^ (row & 7);
        bfv[n][kh] = *reinterpret_cast<const short8*>(&Bs[row * 64 + cs * 8]);
      }
    }
#pragma unroll
    for (int kh = 0; kh < 2; ++kh)
#pragma unroll
      for (int m = 0; m < 4; ++m)
#pragma unroll
        for (int n = 0; n < 4; ++n)
          acc[m][n] = __builtin_amdgcn_mfma_f32_16x16x32_bf16(af[m][kh], bfv[n][kh], acc[m][n], 0, 0, 0);
  }

#pragma unroll
  for (int m = 0; m < 4; ++m) {
#pragma unroll
    for (int n = 0; n < 4; ++n) {
      int grow0 = bm * 128 + wr * 64 + m * 16 + lg * 4;
      int b = grow0 >> 11, nn0 = grow0 & 2047;
      if (isV) {
        int gcol = (bn - 8) * 128 + wc * 64 + n * 16 + lr;
        int h = gcol >> 6, dd = gcol & 63;
        ushort4v pk;
#pragma unroll
        for (int r = 0; r < 4; ++r) pk[r] = f2bf(acc[m][n][r]);
        *reinterpret_cast<ushort4v*>(&vt_out[(((size_t)(b * 16 + h)) * 64 + dd) * 2048 + nn0]) = pk;
      } else {
        int gcol = bn * 128 + wc * 64 + n * 16 + lr;
        int h = gcol >> 6, dd = gcol & 63;
#pragma unroll
        for (int r = 0; r < 4; ++r)
          qk_out[(((size_t)(b * 16 + h)) * 2048 + nn0 + r) * 64 + dd] = f2bf(acc[m][n][r]);
      }
    }
  }
}

// ------- output GEMM: out[m][e] = sum_k w[m][k] * Wout[e][k], fp32 out -------
__global__ __launch_bounds__(256) void gemm_out(const unsigned short* __restrict__ A,
                                                const unsigned short* __restrict__ W,
                                                float* __restrict__ out) {
  __shared__ unsigned short As[128 * 64];
  __shared__ unsigned short Bs[64 * 64];
  const int tid = threadIdx.x;
  const int bm = blockIdx.x & 31;
  const int bn = blockIdx.x >> 5;      // 0..15
  const int lane = tid & 63, wid = tid >> 6;
  const int wr = wid >> 1, wc = wid & 1;
  const int lr = lane & 15, lg = lane >> 4;

  f32x4 acc[4][2] = {};

  const unsigned short* Abase = A + (size_t)bm * 128 * Kc;
  const unsigned short* Wbase = W + (size_t)bn * 64 * Kc;

  for (int kt = 0; kt < Kc / 64; ++kt) {
    __syncthreads();
#pragma unroll
    for (int r = 0; r < 4; ++r) {
      int idx = r * 256 + tid;
      int row = idx >> 3, cc = idx & 7;
      int cs = cc ^ (row & 7);
      gload_lds16(Abase + (size_t)row * Kc + kt * 64 + cs * 8, &As[(r * 256 + wid * 64) * 8]);
    }
#pragma unroll
    for (int r = 0; r < 2; ++r) {
      int idx = r * 256 + tid;
      int row = idx >> 3, cc = idx & 7;
      int cs = cc ^ (row & 7);
      gload_lds16(Wbase + (size_t)row * Kc + kt * 64 + cs * 8, &Bs[(r * 256 + wid * 64) * 8]);
    }
    __syncthreads();

    short8 af[4][2], bfv[2][2];
#pragma unroll
    for (int m = 0; m < 4; ++m) {
      int row = wr * 64 + m * 16 + lr;
#pragma unroll
      for (int kh = 0; kh < 2; ++kh) {
        int cs = (kh * 4 + lg) ^ (row & 7);
        af[m][kh] = *reinterpret_cast<const short8*>(&As[row * 64 + cs * 8]);
      }
    }
#pragma unroll
    for (int n = 0; n < 2; ++n) {
      int row = wc * 32 + n * 16 + lr;
#pragma unroll
      for (int kh = 0; kh < 2; ++kh) {
        int cs = (kh * 4 + lg) ^ (row & 7);
        bfv[n][kh] = *reinterpret_cast<const short8*>(&Bs[row * 64 + cs * 8]);
      }
    }
#pragma unroll
    for (int kh = 0; kh < 2; ++kh)
#pragma unroll
      for (int m = 0; m < 4; ++m)
#pragma unroll
        for (int n = 0; n < 2; ++n)
          acc[m][n] = __builtin_amdgcn_mfma_f32_16x16x32_bf16(af[m][kh], bfv[n][kh], acc[m][n], 0, 0, 0);
  }

#pragma unroll
  for (int m = 0; m < 4; ++m)
#pragma unroll
    for (int n = 0; n < 2; ++n)
#pragma unroll
      for (int r = 0; r < 4; ++r) {
        int grow = bm * 128 + wr * 64 + m * 16 + lg * 4 + r;
        int gcol = bn * 64 + wc * 32 + n * 16 + lr;
        out[(size_t)grow * 1024 + gcol] = acc[m][n][r];
      }
}

// -------- q2l[row] = log2e * ||qk_row||^2 (rows = B*H*N) --------
__global__ __launch_bounds__(256) void q2_kernel(const unsigned short* __restrict__ qk,
                                                 float* __restrict__ q2l) {
  int t = blockIdx.x * 256 + threadIdx.x;
  int row = t >> 2, q = t & 3;
  const short8* p = reinterpret_cast<const short8*>(qk + (size_t)row * 64 + q * 16);
  short8 v0 = p[0], v1 = p[1];
  float s = 0.f;
#pragma unroll
  for (int i = 0; i < 8; ++i) {
    float f0 = bf2f((unsigned short)v0[i]);
    float f1 = bf2f((unsigned short)v1[i]);
    s += f0 * f0 + f1 * f1;
  }
  s += __shfl_xor(s, 1);
  s += __shfl_xor(s, 2);
  if (q == 0) q2l[row] = s * LOG2E;
}

// ---------------- fused distance-attention ----------------
// Wave owns 64 q-rows (2 x 32): K/V LDS fragments amortize over 2 QK^T / 2 PV
// MFMAs -> LDS-pipe cost per q-row halves (R6 showed LDS-throughput-bound).
// p = exp2(2L*s - L*q2i - L*q2j); den = mfma(pa, ones), row-aligned with wacc.
// PARTIAL: K-split x2 (grid 512), f32 partials. FINAL: grid 256, direct out.
template<bool PARTIAL>
__global__ __launch_bounds__(256) void attn_kernel(const unsigned short* __restrict__ qk,
                                                   const unsigned short* __restrict__ vt,
                                                   const float* __restrict__ q2lg_,
                                                   unsigned short* __restrict__ wout,
                                                   float* __restrict__ numP,
                                                   float* __restrict__ denP) {
  __shared__ unsigned short Ks[2][64 * 64];
  __shared__ unsigned short Vs[2][64 * 64];
  __shared__ float q2L[2][64];

  const int tid = threadIdx.x;
  const int chunk = PARTIAL ? 64 : 32;
  const int orig = (blockIdx.x & 7) * chunk + (blockIdx.x >> 3);
  const int half = PARTIAL ? (orig >> 8) : 0;
  const int rest = PARTIAL ? (orig & 255) : orig;
  const int bh = rest >> 3;          // 0..31
  const int qt = rest & 7;           // 8 q-tiles of 256 rows
  const int b = bh >> 4, h = bh & 15;
  const unsigned short* Qg = qk + (size_t)bh * Nc * 64;
  const unsigned short* Vg = vt + (size_t)bh * 64 * Nc;
  const float* q2lg = q2lg_ + (size_t)bh * Nc;
  const int lane = tid & 63, wid = tid >> 6;
  const int lo = lane & 31, hi = lane >> 5;

  const int qbase = qt * 256 + wid * 64;   // wave owns rows [qbase, qbase+64)
  const int kt0 = half * 16;
  const int ktn = PARTIAL ? 16 : 32;

  // Q fragments for both 32-row sub-blocks (B-operand: col=qrow, k=kk*16+hi*8+t)
  short8 qf0[4], qf1[4];
#pragma unroll
  for (int kk = 0; kk < 4; ++kk) {
    qf0[kk] = *reinterpret_cast<const short8*>(
        Qg + (size_t)(qbase + lo) * 64 + kk * 16 + hi * 8);
    qf1[kk] = *reinterpret_cast<const short8*>(
        Qg + (size_t)(qbase + 32 + lo) * 64 + kk * 16 + hi * 8);
  }
  const float q2l_r0 = q2lg[qbase + lo];
  const float q2l_r1 = q2lg[qbase + 32 + lo];

  uint4v ou; ou[0] = 0x3F803F80u; ou[1] = 0x3F803F80u; ou[2] = 0x3F803F80u; ou[3] = 0x3F803F80u;
  const short8 ones = __builtin_bit_cast(short8, ou);

  f32x16 w00 = {}, w01 = {}, w10 = {}, w11 = {}, d0 = {}, d1 = {};

  auto stage = [&](int kt, int s) {
#pragma unroll
    for (int r = 0; r < 2; ++r) {
      int idx = r * 256 + tid;
      int row = idx >> 3, cc = idx & 7;
      int cs = cc ^ (row & 7);
      gload_lds16(Qg + (size_t)(kt * 64 + row) * 64 + cs * 8,
                  &Ks[s][(r * 256 + wid * 64) * 8]);
      gload_lds16(Vg + (size_t)row * Nc + kt * 64 + cs * 8,
                  &Vs[s][(r * 256 + wid * 64) * 8]);
    }
    if (tid < 16) gload_lds16(q2lg + kt * 64 + tid * 4, &q2L[s][0]);
  };

  stage(kt0, 0);
  __syncthreads();

  for (int t = 0; t < ktn; ++t) {
    const int kt = kt0 + t;
    const int cur = t & 1;
    if (t + 1 < ktn) stage(kt + 1, cur ^ 1);

#pragma unroll
    for (int kg = 0; kg < 2; ++kg) {
      // K fragments (A-operand: row=key=kg*32+lo, k=kk*16+hi*8+t)
      short8 kf[4];
#pragma unroll
      for (int kk = 0; kk < 4; ++kk) {
        int row = kg * 32 + lo;
        int c = (kk * 2 + hi) ^ (row & 7);
        kf[kk] = *reinterpret_cast<const short8*>(&Ks[cur][row * 64 + c * 8]);
      }
      f32x16 s0 = {}, s1 = {};
      __builtin_amdgcn_s_setprio(1);
#pragma unroll
      for (int kk = 0; kk < 4; ++kk) {
        s0 = __builtin_amdgcn_mfma_f32_32x32x16_bf16(kf[kk], qf0[kk], s0, 0, 0, 0);
        s1 = __builtin_amdgcn_mfma_f32_32x32x16_bf16(kf[kk], qf1[kk], s1, 0, 0, 0);
      }
      __builtin_amdgcn_s_setprio(0);

      // p = exp2(2L*s - (L*q2_row + L*q2_key)); pack both q-blocks to bf16
      unsigned pk0[8], pk1[8];
#pragma unroll
      for (int q = 0; q < 4; ++q) {
        float4 k2q = *reinterpret_cast<const float4*>(&q2L[cur][kg * 32 + q * 8 + hi * 4]);
        float g0[4], g1[4];
#pragma unroll
        for (int rr = 0; rr < 4; ++rr) {
          int reg = q * 4 + rr;
          float k2 = (rr == 0) ? k2q.x : (rr == 1) ? k2q.y : (rr == 2) ? k2q.z : k2q.w;
          g0[rr] = fexp2(fmaf(s0[reg], 2.0f * LOG2E, -(q2l_r0 + k2)));
          g1[rr] = fexp2(fmaf(s1[reg], 2.0f * LOG2E, -(q2l_r1 + k2)));
        }
        pk0[q * 2]     = cvt_pk_bf16(g0[0], g0[1]);
        pk0[q * 2 + 1] = cvt_pk_bf16(g0[2], g0[3]);
        pk1[q * 2]     = cvt_pk_bf16(g1[0], g1[1]);
        pk1[q * 2 + 1] = cvt_pk_bf16(g1[2], g1[3]);
      }

      // PV + den per 16-key sub-window; V-frags shared by both q-blocks.
      // permlane32_swap(a,b) -> {[a_lo,b_lo],[a_hi,b_hi]} (lane halves).
#pragma unroll
      for (int kkl = 0; kkl < 2; ++kkl) {
        uint2v r00 = __builtin_amdgcn_permlane32_swap(pk0[4 * kkl + 0], pk0[4 * kkl + 2], false, false);
        uint2v r01 = __builtin_amdgcn_permlane32_swap(pk0[4 * kkl + 1], pk0[4 * kkl + 3], false, false);
        uint2v r10 = __builtin_amdgcn_permlane32_swap(pk1[4 * kkl + 0], pk1[4 * kkl + 2], false, false);
        uint2v r11 = __builtin_amdgcn_permlane32_swap(pk1[4 * kkl + 1], pk1[4 * kkl + 3], false, false);
        uint4v u0; u0[0] = r00[0]; u0[1] = r01[0]; u0[2] = r00[1]; u0[3] = r01[1];
        uint4v u1; u1[0] = r10[0]; u1[1] = r11[0]; u1[2] = r10[1]; u1[3] = r11[1];
        short8 pa0 = __builtin_bit_cast(short8, u0);
        short8 pa1 = __builtin_bit_cast(short8, u1);

        __builtin_amdgcn_s_setprio(1);
        d0 = __builtin_amdgcn_mfma_f32_32x32x16_bf16(pa0, ones, d0, 0, 0, 0);
        d1 = __builtin_amdgcn_mfma_f32_32x32x16_bf16(pa1, ones, d1, 0, 0, 0);
#pragma unroll
        for (int dt = 0; dt < 2; ++dt) {
          int row = dt * 32 + lo;
          int c = (kg * 4 + kkl * 2 + hi) ^ (row & 7);
          short8 vfr = *reinterpret_cast<const short8*>(&Vs[cur][row * 64 + c * 8]);
          if (dt == 0) {
            w00 = __builtin_amdgcn_mfma_f32_32x32x16_bf16(pa0, vfr, w00, 0, 0, 0);
            w10 = __builtin_amdgcn_mfma_f32_32x32x16_bf16(pa1, vfr, w10, 0, 0, 0);
          } else {
            w01 = __builtin_amdgcn_mfma_f32_32x32x16_bf16(pa0, vfr, w01, 0, 0, 0);
            w11 = __builtin_amdgcn_mfma_f32_32x32x16_bf16(pa1, vfr, w11, 0, 0, 0);
          }
        }
        __builtin_amdgcn_s_setprio(0);
      }
    }
    __syncthreads();
  }

  if constexpr (PARTIAL) {
    float* numh = numP + (size_t)half * 65536 * 64;
    float* denh = denP + (size_t)half * 65536;
#pragma unroll
    for (int reg = 0; reg < 16; ++reg) {
      int crow = (reg & 3) + 8 * (reg >> 2) + 4 * hi;
      size_t row0 = (size_t)bh * Nc + qbase + crow;
      size_t row1 = row0 + 32;
      numh[row0 * 64 + lo]      = w00[reg];
      numh[row0 * 64 + 32 + lo] = w01[reg];
      numh[row1 * 64 + lo]      = w10[reg];
      numh[row1 * 64 + 32 + lo] = w11[reg];
      if (lo == 0) { denh[row0] = d0[reg]; denh[row1] = d1[reg]; }
    }
  } else {
#pragma unroll
    for (int reg = 0; reg < 16; ++reg) {
      int crow = (reg & 3) + 8 * (reg >> 2) + 4 * hi;
      float iv0 = __builtin_amdgcn_rcpf(d0[reg]);
      float iv1 = __builtin_amdgcn_rcpf(d1[reg]);
      size_t base0 = ((size_t)b * Nc + qbase + crow) * 1024 + h * 64 + lo;
      size_t base1 = ((size_t)b * Nc + qbase + 32 + crow) * 1024 + h * 64 + lo;
      wout[base0]      = f2bf(w00[reg] * iv0);
      wout[base0 + 32] = f2bf(w01[reg] * iv0);
      wout[base1]      = f2bf(w10[reg] * iv1);
      wout[base1 + 32] = f2bf(w11[reg] * iv1);
    }
  }
}

// -------- combine halves: w = (num0+num1)/(den0+den1), scatter to (B,N,D) bf16 --------
__global__ __launch_bounds__(256) void combine_kernel(const float* __restrict__ numP,
                                                      const float* __restrict__ denP,
                                                      unsigned short* __restrict__ wout) {
  int gid = blockIdx.x * 256 + threadIdx.x;   // 524288 threads, 8 d-elems each
  int row = gid >> 3, d0 = (gid & 7) * 8;
  const float* n0 = numP + (size_t)row * 64 + d0;
  const float* n1 = numP + (size_t)65536 * 64 + (size_t)row * 64 + d0;
  float iv = 1.0f / (denP[row] + denP[65536 + row]);
  float4 a0 = *reinterpret_cast<const float4*>(n0);
  float4 a1 = *reinterpret_cast<const float4*>(n0 + 4);
  float4 b0 = *reinterpret_cast<const float4*>(n1);
  float4 b1 = *reinterpret_cast<const float4*>(n1 + 4);
  short8 o;
  o[0] = (short)f2bf((a0.x + b0.x) * iv);
  o[1] = (short)f2bf((a0.y + b0.y) * iv);
  o[2] = (short)f2bf((a0.z + b0.z) * iv);
  o[3] = (short)f2bf((a0.w + b0.w) * iv);
  o[4] = (short)f2bf((a1.x + b1.x) * iv);
  o[5] = (short)f2bf((a1.y + b1.y) * iv);
  o[6] = (short)f2bf((a1.z + b1.z) * iv);
  o[7] = (short)f2bf((a1.w + b1.w) * iv);
  int bh = row >> 11, nn = row & 2047;
  int b = bh >> 4, h = bh & 15;
  *reinterpret_cast<short8*>(&wout[((size_t)b * Nc + nn) * 1024 + h * 64 + d0]) = o;
}

extern "C" void kernel_launch(void* const* d_in, const int* in_sizes, int n_in,
                              void* d_out, int out_size, void* d_ws, size_t ws_size,
                              hipStream_t stream) {
  const float* x    = (const float*)d_in[0];
  const float* Wqk  = (const float*)d_in[1];
  const float* Wv   = (const float*)d_in[2];
  const float* Wout = (const float*)d_in[3];
  float* out = (float*)d_out;
  char* ws = (char*)d_ws;

  unsigned short* x_bf    = (unsigned short*)(ws + 0);          //  8 MB
  unsigned short* wqk_bf  = (unsigned short*)(ws + 8388608);    //  2 MB
  unsigned short* wv_bf   = (unsigned short*)(ws + 10485760);   //  2 MB
  unsigned short* wout_bf = (unsigned short*)(ws + 12582912);   //  2 MB
  unsigned short* qk_buf  = (unsigned short*)(ws + 14680064);   //  8 MB (B,H,N,d)
  unsigned short* vt_buf  = (unsigned short*)(ws + 23068672);   //  8 MB (B,H,d,N)
  float*          q2l_buf = (float*)        (ws + 31457280);    // 256 KB
  unsigned short* w_buf   = (unsigned short*)(ws + 31719424);   //  8 MB (B,N,D)
  float*          num_buf = (float*)        (ws + 40108032);    // 32 MB (2 halves)
  float*          den_buf = (float*)        (ws + 73662464);    // 512 KB (2 halves)
  const size_t need_split = 74186752;

  cvt_bf16<<<2048, 256, 0, stream>>>(x, x_bf, 524288);
  cvt_bf16<<<512, 256, 0, stream>>>(Wqk, wqk_bf, 131072);
  cvt_bf16<<<512, 256, 0, stream>>>(Wv, wv_bf, 131072);
  cvt_bf16<<<512, 256, 0, stream>>>(Wout, wout_bf, 131072);

  gemm_proj<<<512, 256, 0, stream>>>(x_bf, wqk_bf, wv_bf, qk_buf, vt_buf);

  q2_kernel<<<1024, 256, 0, stream>>>(qk_buf, q2l_buf);

  if (ws_size >= need_split) {
    attn_kernel<true><<<512, 256, 0, stream>>>(qk_buf, vt_buf, q2l_buf, nullptr, num_buf, den_buf);
    combine_kernel<<<2048, 256, 0, stream>>>(num_buf, den_buf, w_buf);
  } else {
    attn_kernel<false><<<256, 256, 0, stream>>>(qk_buf, vt_buf, q2l_buf, w_buf, nullptr, nullptr);
  }

  gemm_out<<<512, 256, 0, stream>>>(w_buf, wout_bf, out);
}